// Round 7
// baseline (47810.965 us; speedup 1.0000x reference)
//
#include <hip/hip_runtime.h>
#include <math.h>

// R7: OUTPUT IS FLOAT32. (Inputs: adaptive per-tensor dtype probe, kept from R6.)
// Evidence: R3-R6 (4 different implementations) bit-identical absmax
//   1.292969 = sqrt(2)*max|ref|: my bf16-written output read as f32 pairs
//   compares ref[i] vs my_out[2i+1] (position scramble -> decorrelated, same
//   scale) -> exactly sqrt(2) ceiling; R2's zero bits read as f32 -> 0.914 =
//   max|ref|. "(bf16,...)" label = _any_bf16 from some INPUT being bf16.
// ws ~139 MiB established safe. Structure: naive reference-mirroring (R5/R6);
// optimize only after first PASS.

#define BATCH 1024
typedef unsigned short u16;
typedef unsigned int uint;

__device__ __forceinline__ float b2f(u16 v) {
    return __uint_as_float(((uint)v) << 16);
}
__device__ __forceinline__ u16 f2b(float f) {  // RNE
    uint u = __float_as_uint(f);
    return (u16)((u + 0x7FFFu + ((u >> 16) & 1u)) >> 16);
}
// adaptive load: isbf ? bf16[i] : f32[i]
__device__ __forceinline__ float ldf(const void* p, long long i, int isbf) {
    return isbf ? b2f(((const u16*)p)[i]) : ((const float*)p)[i];
}

struct Ptrs { const void* p[24]; int sz[24]; };

// ---------------- dtype probe: one block per tensor ----------------
__global__ __launch_bounds__(256) void probe_dtype(Ptrs P, int* __restrict__ flags)
{
    int t = blockIdx.x;
    bool ones = (t == 2 || t == 5 || t == 8 || t == 11 || t == 14 || t == 17);
    bool inh  = (t == 3 || t == 6 || t == 9 || t == 12 || t == 15 || t == 18 || t == 20);
    if (inh) return;
    const u16* q = (const u16*)P.p[t];
    if (ones) {
        if (threadIdx.x == 0) {
            uint w0 = *(const uint*)q;
            flags[t] = (w0 == 0x3F803F80u) ? 1 : 0;  // bf16 ones pair vs f32 1.0
        }
        return;
    }
    int n = P.sz[t]; if (n > 4096) n = 4096;
    __shared__ int cnt;
    if (threadIdx.x == 0) cnt = 0;
    __syncthreads();
    int local = 0;
    for (int i = threadIdx.x; i < n; i += 256) {
        uint e = (q[i] >> 7) & 0xFFu;
        if (!(e == 0u || (e >= 100u && e <= 140u))) local++;
    }
    atomicAdd(&cnt, local);
    __syncthreads();
    if (threadIdx.x == 0) flags[t] = (cnt * 8 > n) ? 0 : 1;  // many absurd exps -> f32
}

__global__ void fixup_flags(int* __restrict__ flags)
{
    if (threadIdx.x == 0) {
        flags[3] = flags[2];  flags[6] = flags[5];  flags[9] = flags[8];
        flags[12] = flags[11]; flags[15] = flags[14]; flags[18] = flags[17];
        flags[20] = flags[19];
    }
}

// ---------------- cast input -> bf16 (layout-preserving) ----------------
__global__ __launch_bounds__(256) void cast_in(
    const void* __restrict__ x, u16* __restrict__ X0, int n, const int* __restrict__ flags)
{
    int fx = flags[0];
    int i = blockIdx.x * 256 + threadIdx.x;
    if (i < n) X0[i] = f2b(ldf(x, i, fx));
}

// ---------------- naive deformable conv (adaptive W/coords) ----------------
// X: bf16 [B, Cin, H, W]; Wt raw [Cout, Cin, 3, 3]; Y: bf16 [B, Cout, H, W]
__global__ __launch_bounds__(256) void conv_naive(
    const u16* __restrict__ X, const void* __restrict__ Wt,
    u16* __restrict__ Y, const void* __restrict__ coords,
    int B, int Cin, int Cout, int H, int W,
    const int* __restrict__ flags, int wslot, int cslot)
{
    int fw = flags[wslot], fcd = flags[cslot];
    int HW = H * W;
    long long total = (long long)B * Cout * HW;
    long long gid = (long long)blockIdx.x * 256 + threadIdx.x;
    if (gid >= total) return;
    int p = (int)(gid % HW);
    int t = (int)(gid / HW);   // b*Cout + o
    int o = t % Cout;
    int b = t / Cout;
    int h = p / W, w = p % W;

    const u16* Xb = X + (size_t)b * Cin * HW;

    float acc = 0.0f;
#pragma unroll
    for (int k = 0; k < 9; ++k) {
        int kh = k / 3, kw = k % 3;
        float py = (float)(h - 1 + kh) + ldf(coords, p * 18 + 2 * k, fcd);
        float px = (float)(w - 1 + kw) + ldf(coords, p * 18 + 2 * k + 1, fcd);
        float y0f = floorf(py), x0f = floorf(px);
        float wy1 = py - y0f, wy0 = 1.0f - wy1;
        float wx1 = px - x0f, wx0 = 1.0f - wx1;
        int y0 = (int)y0f, x0 = (int)x0f;
        int ii[4]; float ww[4];
#pragma unroll
        for (int j = 0; j < 4; ++j) {
            int dy = j >> 1, dx = j & 1;
            int yy = y0 + dy, xx = x0 + dx;
            bool valid = (yy >= 0) && (yy < H) && (xx >= 0) && (xx < W);
            int yc = min(max(yy, 0), H - 1);
            int xc = min(max(xx, 0), W - 1);
            ii[j] = yc * W + xc;
            ww[j] = valid ? (dy ? wy1 : wy0) * (dx ? wx1 : wx0) : 0.0f;
        }
        for (int c = 0; c < Cin; ++c) {
            const u16* Xc = Xb + (size_t)c * HW;
            float sample = ww[0] * b2f(Xc[ii[0]]) + ww[1] * b2f(Xc[ii[1]])
                         + ww[2] * b2f(Xc[ii[2]]) + ww[3] * b2f(Xc[ii[3]]);
            acc = fmaf(sample, ldf(Wt, (size_t)o * Cin * 9 + c * 9 + k, fw), acc);
        }
    }
    Y[gid] = f2b(acc);
}

// ---------------- BN stats ----------------
__global__ __launch_bounds__(256) void bn_stats_naive(
    const u16* __restrict__ Y, float* __restrict__ stats, int C, int HW)
{
    int bc = blockIdx.x;           // b*C + c
    int c = bc % C;
    const u16* Yp = Y + (size_t)bc * HW;
    float s = 0.f, ss = 0.f;
    for (int i = threadIdx.x; i < HW; i += 256) {
        float v = b2f(Yp[i]);
        s += v; ss += v * v;
    }
#pragma unroll
    for (int off = 32; off > 0; off >>= 1) {
        s += __shfl_down(s, off);
        ss += __shfl_down(ss, off);
    }
    __shared__ float ls[4], lss[4];
    int wid = threadIdx.x >> 6, lane = threadIdx.x & 63;
    if (lane == 0) { ls[wid] = s; lss[wid] = ss; }
    __syncthreads();
    if (threadIdx.x == 0) {
        float S = (ls[0] + ls[1]) + (ls[2] + ls[3]);
        float SS = (lss[0] + lss[1]) + (lss[2] + lss[3]);
        atomicAdd(&stats[2 * c], S);
        atomicAdd(&stats[2 * c + 1], SS);
    }
}

// ---------------- BN apply + ReLU (adaptive gamma/beta) ----------------
__global__ __launch_bounds__(256) void bn_apply_naive(
    u16* __restrict__ Y, const float* __restrict__ stats,
    const void* __restrict__ gamma, const void* __restrict__ beta,
    int C, int HW, float invN, long long total,
    const int* __restrict__ flags, int gslot, int bslot)
{
    int fg = flags[gslot], fb = flags[bslot];
    long long i = (long long)blockIdx.x * 256 + threadIdx.x;
    if (i >= total) return;
    int c = (int)((i / HW) % C);
    float mean = stats[2 * c] * invN;
    float var = stats[2 * c + 1] * invN - mean * mean;
    float sc = ldf(gamma, c, fg) * rsqrtf(var + 1e-5f);
    float sh = ldf(beta, c, fb) - mean * sc;
    float v = b2f(Y[i]);
    Y[i] = f2b(fmaxf(fmaf(v, sc, sh), 0.0f));
}

// ---------------- 2x2 maxpool ----------------
__global__ __launch_bounds__(256) void maxpool_naive(
    const u16* __restrict__ A, u16* __restrict__ P, int H2, int W2, long long total)
{
    long long i = (long long)blockIdx.x * 256 + threadIdx.x;
    if (i >= total) return;
    int p2 = (int)(i % (H2 * W2));
    long long bc = i / (H2 * W2);
    int h2 = p2 / W2, w2 = p2 % W2;
    const u16* Ab = A + bc * (4LL * H2 * W2);
    int W = 2 * W2;
    float m = fmaxf(
        fmaxf(b2f(Ab[(2 * h2) * W + 2 * w2]),     b2f(Ab[(2 * h2) * W + 2 * w2 + 1])),
        fmaxf(b2f(Ab[(2 * h2 + 1) * W + 2 * w2]), b2f(Ab[(2 * h2 + 1) * W + 2 * w2 + 1])));
    P[i] = f2b(m);
}

// ---------------- global avg: [B,128,64] -> f32 [B,128] ----------------
__global__ __launch_bounds__(256) void avgpool_naive(
    const u16* __restrict__ A, float* __restrict__ M, long long total)
{
    long long i = (long long)blockIdx.x * 256 + threadIdx.x;
    if (i >= total) return;     // i = b*128 + c
    const u16* Ap = A + i * 64;
    float s = 0.f;
#pragma unroll
    for (int p = 0; p < 64; ++p) s += b2f(Ap[p]);
    M[i] = s * (1.0f / 64.0f);
}

// ---------------- FC: out f32 [B,10] ----------------
__global__ __launch_bounds__(256) void fc_naive(
    const float* __restrict__ M, const void* __restrict__ fcw,
    const void* __restrict__ fcb, float* __restrict__ out, int total,
    const int* __restrict__ flags)
{
    int fw = flags[19], fb = flags[20];
    int i = blockIdx.x * 256 + threadIdx.x;
    if (i >= total) return;     // i = b*10 + o
    int o = i % 10, b = i / 10;
    float acc = ldf(fcb, o, fb);
    const float* Mb = M + (size_t)b * 128;
    for (int c = 0; c < 128; ++c) acc = fmaf(Mb[c], ldf(fcw, (size_t)o * 128 + c, fw), acc);
    out[i] = acc;   // FLOAT32 output
}

// ---------------- sentinel (f32) ----------------
__global__ __launch_bounds__(256) void sentinel_k(float* out, int n, float v) {
    int i = blockIdx.x * 256 + threadIdx.x;
    if (i < n) out[i] = v;
}

extern "C" void kernel_launch(void* const* d_in, const int* in_sizes, int n_in,
                              void* d_out, int out_size, void* d_ws, size_t ws_size,
                              hipStream_t stream) {
    float* out = (float*)d_out;

    static const int exp_sizes[24] = {
        1024 * 1024,
        288, 32, 32,   9216, 32, 32,   18432, 64, 64,   36864, 64, 64,
        73728, 128, 128,   147456, 128, 128,
        1280, 10,   18432, 4608, 1152
    };
    float bad = 0.0f;
    if (n_in != 24) bad = 1000.0f;
    else {
        for (int i = 0; i < 24; ++i)
            if (in_sizes[i] != exp_sizes[i]) { bad = 2000.0f + 16.0f * i; break; }
    }
    if (bad != 0.0f) {
        sentinel_k<<<(out_size + 255) / 256, 256, 0, stream>>>(out, out_size, bad);
        return;
    }

    Ptrs P;
    for (int i = 0; i < 24; ++i) { P.p[i] = d_in[i]; P.sz[i] = in_sizes[i]; }

    char* wsb = (char*)d_ws;
    size_t off = 0;
    auto take = [&](size_t bytes) -> void* {
        void* pp = wsb + off;
        off += (bytes + 255) & ~(size_t)255;
        return pp;
    };
    int*   flags = (int*)  take(32 * 4);
    float* stats = (float*)take(6 * 256 * 4);
    u16*   X0    = (u16*)  take((size_t)1024 * 1024 * 2);
    float* M     = (float*)take((size_t)BATCH * 128 * 4);
    u16*   bufA  = (u16*)  take((size_t)BATCH * 32 * 1024 * 2);
    u16*   bufB  = (u16*)  take((size_t)BATCH * 32 * 1024 * 2);

    if (ws_size < off) {
        sentinel_k<<<(out_size + 255) / 256, 256, 0, stream>>>(out, out_size, 12345.0f);
        return;
    }

    probe_dtype<<<24, 256, 0, stream>>>(P, flags);
    fixup_flags<<<1, 64, 0, stream>>>(flags);
    hipMemsetAsync(stats, 0, 6 * 256 * 4, stream);
    cast_in<<<(1048576 + 255) / 256, 256, 0, stream>>>(d_in[0], X0, 1048576, flags);

    long long t;
    // L11
    t = (long long)BATCH * 32 * 1024;
    conv_naive<<<(int)((t + 255) / 256), 256, 0, stream>>>(X0, d_in[1], bufA, d_in[21], BATCH, 1, 32, 32, 32, flags, 1, 21);
    bn_stats_naive<<<BATCH * 32, 256, 0, stream>>>(bufA, stats + 0 * 256, 32, 1024);
    bn_apply_naive<<<(int)((t + 255) / 256), 256, 0, stream>>>(bufA, stats + 0 * 256, d_in[2], d_in[3], 32, 1024, 1.0f / (1024.0f * 1024.0f), t, flags, 2, 3);
    // L12
    conv_naive<<<(int)((t + 255) / 256), 256, 0, stream>>>(bufA, d_in[4], bufB, d_in[21], BATCH, 32, 32, 32, 32, flags, 4, 21);
    bn_stats_naive<<<BATCH * 32, 256, 0, stream>>>(bufB, stats + 1 * 256, 32, 1024);
    bn_apply_naive<<<(int)((t + 255) / 256), 256, 0, stream>>>(bufB, stats + 1 * 256, d_in[5], d_in[6], 32, 1024, 1.0f / (1024.0f * 1024.0f), t, flags, 5, 6);
    // pool -> bufA [B,32,16,16]
    t = (long long)BATCH * 32 * 256;
    maxpool_naive<<<(int)((t + 255) / 256), 256, 0, stream>>>(bufB, bufA, 16, 16, t);
    // L21
    t = (long long)BATCH * 64 * 256;
    conv_naive<<<(int)((t + 255) / 256), 256, 0, stream>>>(bufA, d_in[7], bufB, d_in[22], BATCH, 32, 64, 16, 16, flags, 7, 22);
    bn_stats_naive<<<BATCH * 64, 256, 0, stream>>>(bufB, stats + 2 * 256, 64, 256);
    bn_apply_naive<<<(int)((t + 255) / 256), 256, 0, stream>>>(bufB, stats + 2 * 256, d_in[8], d_in[9], 64, 256, 1.0f / (1024.0f * 256.0f), t, flags, 8, 9);
    // L22
    conv_naive<<<(int)((t + 255) / 256), 256, 0, stream>>>(bufB, d_in[10], bufA, d_in[22], BATCH, 64, 64, 16, 16, flags, 10, 22);
    bn_stats_naive<<<BATCH * 64, 256, 0, stream>>>(bufA, stats + 3 * 256, 64, 256);
    bn_apply_naive<<<(int)((t + 255) / 256), 256, 0, stream>>>(bufA, stats + 3 * 256, d_in[11], d_in[12], 64, 256, 1.0f / (1024.0f * 256.0f), t, flags, 11, 12);
    // pool -> bufB [B,64,8,8]
    t = (long long)BATCH * 64 * 64;
    maxpool_naive<<<(int)((t + 255) / 256), 256, 0, stream>>>(bufA, bufB, 8, 8, t);
    // L31
    t = (long long)BATCH * 128 * 64;
    conv_naive<<<(int)((t + 255) / 256), 256, 0, stream>>>(bufB, d_in[13], bufA, d_in[23], BATCH, 64, 128, 8, 8, flags, 13, 23);
    bn_stats_naive<<<BATCH * 128, 256, 0, stream>>>(bufA, stats + 4 * 256, 128, 64);
    bn_apply_naive<<<(int)((t + 255) / 256), 256, 0, stream>>>(bufA, stats + 4 * 256, d_in[14], d_in[15], 128, 64, 1.0f / (1024.0f * 64.0f), t, flags, 14, 15);
    // L32
    conv_naive<<<(int)((t + 255) / 256), 256, 0, stream>>>(bufA, d_in[16], bufB, d_in[23], BATCH, 128, 128, 8, 8, flags, 16, 23);
    bn_stats_naive<<<BATCH * 128, 256, 0, stream>>>(bufB, stats + 5 * 256, 128, 64);
    bn_apply_naive<<<(int)((t + 255) / 256), 256, 0, stream>>>(bufB, stats + 5 * 256, d_in[17], d_in[18], 128, 64, 1.0f / (1024.0f * 64.0f), t, flags, 17, 18);
    // avg + FC (f32 out)
    t = (long long)BATCH * 128;
    avgpool_naive<<<(int)((t + 255) / 256), 256, 0, stream>>>(bufB, M, t);
    fc_naive<<<(BATCH * 10 + 255) / 256, 256, 0, stream>>>(M, d_in[19], d_in[20], out, BATCH * 10, flags);
}

// Round 8
// 2031.196 us; speedup vs baseline: 23.5383x; 23.5383x over previous
//
#include <hip/hip_runtime.h>
#include <math.h>

// R8: fast batch-inner pipeline (math proven correct in R4/R5; output f32 per R7).
//   Layout: activations [C, HW, B] bf16, B=1024 innermost (batch-coalesced).
//   Conv: block = (position p, 16-cout group); 256 thr = 1024 batch / ushort4.
//   Sampling indices block-uniform -> coalesced vec loads, reused x16 couts.
//   Weights prepped to f32 [Cin][9][Cout]. Adaptive input dtype probe kept (R6/R7).
// R7 counters: conv_naive VALUBusy 40%, HBM 0.06%, scalar-gather-bound 47.8 ms.

#define BATCH 1024
typedef unsigned short u16;
typedef unsigned int uint;

__device__ __forceinline__ float b2f(u16 v) {
    return __uint_as_float(((uint)v) << 16);
}
__device__ __forceinline__ float4 b2f4(ushort4 v) {
    return make_float4(b2f(v.x), b2f(v.y), b2f(v.z), b2f(v.w));
}
__device__ __forceinline__ u16 f2b(float f) {  // RNE
    uint u = __float_as_uint(f);
    return (u16)((u + 0x7FFFu + ((u >> 16) & 1u)) >> 16);
}
__device__ __forceinline__ float ldf(const void* p, long long i, int isbf) {
    return isbf ? b2f(((const u16*)p)[i]) : ((const float*)p)[i];
}

struct Ptrs { const void* p[24]; int sz[24]; };

// ---------------- dtype probe (kept from R6/R7, proven) ----------------
__global__ __launch_bounds__(256) void probe_dtype(Ptrs P, int* __restrict__ flags)
{
    int t = blockIdx.x;
    bool ones = (t == 2 || t == 5 || t == 8 || t == 11 || t == 14 || t == 17);
    bool inh  = (t == 3 || t == 6 || t == 9 || t == 12 || t == 15 || t == 18 || t == 20);
    if (inh) return;
    const u16* q = (const u16*)P.p[t];
    if (ones) {
        if (threadIdx.x == 0) {
            uint w0 = *(const uint*)q;
            flags[t] = (w0 == 0x3F803F80u) ? 1 : 0;
        }
        return;
    }
    int n = P.sz[t]; if (n > 4096) n = 4096;
    __shared__ int cnt;
    if (threadIdx.x == 0) cnt = 0;
    __syncthreads();
    int local = 0;
    for (int i = threadIdx.x; i < n; i += 256) {
        uint e = (q[i] >> 7) & 0xFFu;
        if (!(e == 0u || (e >= 100u && e <= 140u))) local++;
    }
    atomicAdd(&cnt, local);
    __syncthreads();
    if (threadIdx.x == 0) flags[t] = (cnt * 8 > n) ? 0 : 1;
}

__global__ void fixup_flags(int* __restrict__ flags)
{
    if (threadIdx.x == 0) {
        flags[3] = flags[2];  flags[6] = flags[5];  flags[9] = flags[8];
        flags[12] = flags[11]; flags[15] = flags[14]; flags[18] = flags[17];
        flags[20] = flags[19];
    }
}

// ---------------- input: [B,1,32,32] -> bf16 [1024 pos, B] ----------------
__global__ __launch_bounds__(256) void transpose_in(
    const void* __restrict__ x, u16* __restrict__ X0, const int* __restrict__ flags)
{
    int fx = flags[0];
    int p = blockIdx.x;      // 0..1023
    int t = threadIdx.x;     // 0..255
    ushort4 v;
    v.x = f2b(ldf(x, (long long)(4 * t + 0) * 1024 + p, fx));
    v.y = f2b(ldf(x, (long long)(4 * t + 1) * 1024 + p, fx));
    v.z = f2b(ldf(x, (long long)(4 * t + 2) * 1024 + p, fx));
    v.w = f2b(ldf(x, (long long)(4 * t + 3) * 1024 + p, fx));
    ((ushort4*)(X0 + (size_t)p * BATCH))[t] = v;
}

// ---------------- weight prep: [Cout][Cin][3][3] -> f32 [Cin][9][Cout] ----------------
__global__ __launch_bounds__(256) void prep_w(
    const void* __restrict__ W, float* __restrict__ W2, int Cout, int Cin,
    const int* __restrict__ flags, int slot)
{
    int fw = flags[slot];
    int i = blockIdx.x * 256 + threadIdx.x;
    int n = Cout * Cin * 9;
    if (i >= n) return;
    int o = i / (Cin * 9);
    int r = i % (Cin * 9);
    int c = r / 9, k = r % 9;
    W2[(c * 9 + k) * Cout + o] = ldf(W, i, fw);
}

// ---------------- deformable conv, batch-inner ----------------
// X: bf16 [Cin, HW, B]; W2: f32 [Cin, 9, Cout]; Y: bf16 [Cout, HW, B]
// coords raw [H,W,18] (adaptive). grid: (HW, Cout/16); 256 thr = B/4.
#define CB 16
__global__ __launch_bounds__(256) void deform_conv(
    const u16* __restrict__ X, const float* __restrict__ W2,
    u16* __restrict__ Y, const void* __restrict__ coords,
    int Cin, int H, int W, int Cout,
    const int* __restrict__ flags, int cslot)
{
    const int fcd = flags[cslot];
    const int HW = H * W;
    const int p = blockIdx.x;
    const int h = p / W, w = p % W;
    const int oBase = blockIdx.y * CB;
    const int b4 = threadIdx.x;

    float4 acc[CB];
#pragma unroll
    for (int o = 0; o < CB; ++o) acc[o] = make_float4(0.f, 0.f, 0.f, 0.f);

#pragma unroll
    for (int k = 0; k < 9; ++k) {
        int kh = k / 3, kw = k % 3;
        float py = (float)(h - 1 + kh) + ldf(coords, p * 18 + 2 * k, fcd);
        float px = (float)(w - 1 + kw) + ldf(coords, p * 18 + 2 * k + 1, fcd);
        float y0f = floorf(py), x0f = floorf(px);
        float wy1 = py - y0f, wy0 = 1.0f - wy1;
        float wx1 = px - x0f, wx0 = 1.0f - wx1;
        int y0 = (int)y0f, x0 = (int)x0f;
        int ii[4]; float ww[4];
#pragma unroll
        for (int j = 0; j < 4; ++j) {
            int dy = j >> 1, dx = j & 1;
            int yy = y0 + dy, xx = x0 + dx;
            bool valid = (yy >= 0) && (yy < H) && (xx >= 0) && (xx < W);
            int yc = min(max(yy, 0), H - 1);
            int xc = min(max(xx, 0), W - 1);
            ii[j] = yc * W + xc;
            ww[j] = valid ? (dy ? wy1 : wy0) * (dx ? wx1 : wx0) : 0.0f;
        }
        for (int c = 0; c < Cin; ++c) {
            const ushort4* Xc = (const ushort4*)(X + (size_t)c * HW * BATCH);
            float4 v0 = b2f4(Xc[ii[0] * 256 + b4]);
            float4 v1 = b2f4(Xc[ii[1] * 256 + b4]);
            float4 v2 = b2f4(Xc[ii[2] * 256 + b4]);
            float4 v3 = b2f4(Xc[ii[3] * 256 + b4]);
            float4 s;
            s.x = ww[0] * v0.x + ww[1] * v1.x + ww[2] * v2.x + ww[3] * v3.x;
            s.y = ww[0] * v0.y + ww[1] * v1.y + ww[2] * v2.y + ww[3] * v3.y;
            s.z = ww[0] * v0.z + ww[1] * v1.z + ww[2] * v2.z + ww[3] * v3.z;
            s.w = ww[0] * v0.w + ww[1] * v1.w + ww[2] * v2.w + ww[3] * v3.w;
            const float* wc = W2 + ((size_t)c * 9 + k) * Cout + oBase;
#pragma unroll
            for (int o = 0; o < CB; ++o) {
                float wv = wc[o];
                acc[o].x = fmaf(wv, s.x, acc[o].x);
                acc[o].y = fmaf(wv, s.y, acc[o].y);
                acc[o].z = fmaf(wv, s.z, acc[o].z);
                acc[o].w = fmaf(wv, s.w, acc[o].w);
            }
        }
    }
#pragma unroll
    for (int o = 0; o < CB; ++o) {
        ushort4 r;
        r.x = f2b(acc[o].x); r.y = f2b(acc[o].y);
        r.z = f2b(acc[o].z); r.w = f2b(acc[o].w);
        ((ushort4*)(Y + ((size_t)(oBase + o) * HW + p) * BATCH))[b4] = r;
    }
}

// ---------------- BN stats: [C, N8*8] bf16 -> per-channel sum/sumsq ----------------
__global__ __launch_bounds__(256) void bn_stats(
    const u16* __restrict__ Y, float* __restrict__ stats, int N8)
{
    int c = blockIdx.x;
    const uint4* Yc = (const uint4*)(Y + (size_t)c * N8 * 8);
    float s = 0.f, ss = 0.f;
    for (int i = blockIdx.y * 256 + threadIdx.x; i < N8; i += gridDim.y * 256) {
        uint4 v = Yc[i];
        uint ua[4] = {v.x, v.y, v.z, v.w};
#pragma unroll
        for (int j = 0; j < 4; ++j) {
            float lo = __uint_as_float(ua[j] << 16);
            float hi = __uint_as_float(ua[j] & 0xFFFF0000u);
            s += lo + hi;
            ss += lo * lo + hi * hi;
        }
    }
#pragma unroll
    for (int off = 32; off > 0; off >>= 1) {
        s += __shfl_down(s, off);
        ss += __shfl_down(ss, off);
    }
    __shared__ float ls[4], lss[4];
    int wid = threadIdx.x >> 6, lane = threadIdx.x & 63;
    if (lane == 0) { ls[wid] = s; lss[wid] = ss; }
    __syncthreads();
    if (threadIdx.x == 0) {
        float S = (ls[0] + ls[1]) + (ls[2] + ls[3]);
        float SS = (lss[0] + lss[1]) + (lss[2] + lss[3]);
        atomicAdd(&stats[2 * c], S);
        atomicAdd(&stats[2 * c + 1], SS);
    }
}

// ---------------- BN apply + ReLU (in place; adaptive gamma/beta) ----------------
__global__ __launch_bounds__(256) void bn_apply(
    u16* __restrict__ Y, const float* __restrict__ stats,
    const void* __restrict__ gamma, const void* __restrict__ beta, int N8,
    const int* __restrict__ flags, int gslot, int bslot)
{
    int c = blockIdx.y;
    float invN = 1.0f / ((float)N8 * 8.0f);
    float mean = stats[2 * c] * invN;
    float var = stats[2 * c + 1] * invN - mean * mean;
    float sc = ldf(gamma, c, flags[gslot]) * rsqrtf(var + 1e-5f);
    float sh = ldf(beta, c, flags[bslot]) - mean * sc;
    uint4* Yc = (uint4*)(Y + (size_t)c * N8 * 8);
    for (int i = blockIdx.x * 256 + threadIdx.x; i < N8; i += gridDim.x * 256) {
        uint4 v = Yc[i];
        uint ua[4] = {v.x, v.y, v.z, v.w};
#pragma unroll
        for (int j = 0; j < 4; ++j) {
            float lo = __uint_as_float(ua[j] << 16);
            float hi = __uint_as_float(ua[j] & 0xFFFF0000u);
            lo = fmaxf(fmaf(lo, sc, sh), 0.f);
            hi = fmaxf(fmaf(hi, sc, sh), 0.f);
            ua[j] = ((uint)f2b(hi) << 16) | (uint)f2b(lo);
        }
        v.x = ua[0]; v.y = ua[1]; v.z = ua[2]; v.w = ua[3];
        Yc[i] = v;
    }
}

// ---------------- 2x2 maxpool on bf16 [C,H,W,B] ----------------
__global__ __launch_bounds__(128) void maxpool2k(
    const u16* __restrict__ A, u16* __restrict__ P, int H2, int W2)
{
    int c = blockIdx.y;
    int p = blockIdx.x;
    int h2 = p / W2, w2 = p % W2;
    int W = W2 * 2;
    int b8 = threadIdx.x;  // 0..127
    const uint4* Ac = (const uint4*)(A + (size_t)c * (4 * H2 * W2) * BATCH);
    int p00 = (2 * h2) * W + 2 * w2;
    uint4 va = Ac[(size_t)p00 * 128 + b8];
    uint4 vb = Ac[(size_t)(p00 + 1) * 128 + b8];
    uint4 vd = Ac[(size_t)(p00 + W) * 128 + b8];
    uint4 ve = Ac[(size_t)(p00 + W + 1) * 128 + b8];
    uint ra[4] = {va.x, va.y, va.z, va.w};
    uint rb[4] = {vb.x, vb.y, vb.z, vb.w};
    uint rd[4] = {vd.x, vd.y, vd.z, vd.w};
    uint re[4] = {ve.x, ve.y, ve.z, ve.w};
    uint ro[4];
#pragma unroll
    for (int j = 0; j < 4; ++j) {
        float lo = fmaxf(fmaxf(__uint_as_float(ra[j] << 16), __uint_as_float(rb[j] << 16)),
                         fmaxf(__uint_as_float(rd[j] << 16), __uint_as_float(re[j] << 16)));
        float hi = fmaxf(fmaxf(__uint_as_float(ra[j] & 0xFFFF0000u), __uint_as_float(rb[j] & 0xFFFF0000u)),
                         fmaxf(__uint_as_float(rd[j] & 0xFFFF0000u), __uint_as_float(re[j] & 0xFFFF0000u)));
        ro[j] = ((uint)f2b(hi) << 16) | (uint)f2b(lo);
    }
    uint4 m; m.x = ro[0]; m.y = ro[1]; m.z = ro[2]; m.w = ro[3];
    ((uint4*)(P + ((size_t)c * H2 * W2 + p) * BATCH))[b8] = m;
}

// ---------------- global avg over 64 positions: [128,64,B] -> f32 [128,B] ----------------
__global__ __launch_bounds__(128) void avgpool8(
    const u16* __restrict__ A, float* __restrict__ M)
{
    int c = blockIdx.x;
    int b8 = threadIdx.x;  // 0..127
    const uint4* Ac = (const uint4*)(A + (size_t)c * 64 * BATCH);
    float acc[8];
#pragma unroll
    for (int j = 0; j < 8; ++j) acc[j] = 0.f;
    for (int p = 0; p < 64; ++p) {
        uint4 v = Ac[(size_t)p * 128 + b8];
        uint ua[4] = {v.x, v.y, v.z, v.w};
#pragma unroll
        for (int j = 0; j < 4; ++j) {
            acc[2 * j] += __uint_as_float(ua[j] << 16);
            acc[2 * j + 1] += __uint_as_float(ua[j] & 0xFFFF0000u);
        }
    }
    float* Mo = M + (size_t)c * BATCH + 8 * b8;
#pragma unroll
    for (int j = 0; j < 8; ++j) Mo[j] = acc[j] * (1.0f / 64.0f);
}

// ---------------- FC: out f32 [B,10]; M [128,B] ----------------
__global__ __launch_bounds__(256) void fc_kernel(
    const float* __restrict__ M, const void* __restrict__ fcw,
    const void* __restrict__ fcb, float* __restrict__ out,
    const int* __restrict__ flags)
{
    int fw = flags[19], fb = flags[20];
    int o = blockIdx.x;   // 0..9
    int b4 = threadIdx.x; // 0..255
    float bias = ldf(fcb, o, fb);
    float4 acc = make_float4(bias, bias, bias, bias);
    for (int c = 0; c < 128; ++c) {
        float wv = ldf(fcw, o * 128 + c, fw);
        float4 m = ((const float4*)(M + (size_t)c * BATCH))[b4];
        acc.x = fmaf(wv, m.x, acc.x);
        acc.y = fmaf(wv, m.y, acc.y);
        acc.z = fmaf(wv, m.z, acc.z);
        acc.w = fmaf(wv, m.w, acc.w);
    }
    out[(size_t)(4 * b4 + 0) * 10 + o] = acc.x;
    out[(size_t)(4 * b4 + 1) * 10 + o] = acc.y;
    out[(size_t)(4 * b4 + 2) * 10 + o] = acc.z;
    out[(size_t)(4 * b4 + 3) * 10 + o] = acc.w;
}

// ---------------- sentinel (f32) ----------------
__global__ __launch_bounds__(256) void sentinel_k(float* out, int n, float v) {
    int i = blockIdx.x * 256 + threadIdx.x;
    if (i < n) out[i] = v;
}

extern "C" void kernel_launch(void* const* d_in, const int* in_sizes, int n_in,
                              void* d_out, int out_size, void* d_ws, size_t ws_size,
                              hipStream_t stream) {
    float* out = (float*)d_out;

    static const int exp_sizes[24] = {
        1024 * 1024,
        288, 32, 32,   9216, 32, 32,   18432, 64, 64,   36864, 64, 64,
        73728, 128, 128,   147456, 128, 128,
        1280, 10,   18432, 4608, 1152
    };
    float bad = 0.0f;
    if (n_in != 24) bad = 1000.0f;
    else {
        for (int i = 0; i < 24; ++i)
            if (in_sizes[i] != exp_sizes[i]) { bad = 2000.0f + 16.0f * i; break; }
    }
    if (bad != 0.0f) {
        sentinel_k<<<(out_size + 255) / 256, 256, 0, stream>>>(out, out_size, bad);
        return;
    }

    Ptrs P;
    for (int i = 0; i < 24; ++i) { P.p[i] = d_in[i]; P.sz[i] = in_sizes[i]; }

    char* wsb = (char*)d_ws;
    size_t off = 0;
    auto take = [&](size_t bytes) -> void* {
        void* pp = wsb + off;
        off += (bytes + 255) & ~(size_t)255;
        return pp;
    };
    int*   flags = (int*)  take(32 * 4);
    float* stats = (float*)take(6 * 256 * 4);
    float* w11p  = (float*)take(32 * 1 * 9 * 4);
    float* w12p  = (float*)take(32 * 32 * 9 * 4);
    float* w21p  = (float*)take(64 * 32 * 9 * 4);
    float* w22p  = (float*)take(64 * 64 * 9 * 4);
    float* w31p  = (float*)take(128 * 64 * 9 * 4);
    float* w32p  = (float*)take(128 * 128 * 9 * 4);
    u16*   X0    = (u16*)  take((size_t)1024 * BATCH * 2);
    float* M     = (float*)take((size_t)128 * BATCH * 4);
    u16*   bufA  = (u16*)  take((size_t)32 * 1024 * BATCH * 2);   // 64 MiB
    u16*   bufB  = (u16*)  take((size_t)32 * 1024 * BATCH * 2);   // 64 MiB

    if (ws_size < off) {
        sentinel_k<<<(out_size + 255) / 256, 256, 0, stream>>>(out, out_size, 12345.0f);
        return;
    }

    probe_dtype<<<24, 256, 0, stream>>>(P, flags);
    fixup_flags<<<1, 64, 0, stream>>>(flags);
    hipMemsetAsync(stats, 0, 6 * 256 * 4, stream);
    transpose_in<<<1024, 256, 0, stream>>>(d_in[0], X0, flags);
    prep_w<<<(32 * 1 * 9 + 255) / 256, 256, 0, stream>>>(d_in[1], w11p, 32, 1, flags, 1);
    prep_w<<<(32 * 32 * 9 + 255) / 256, 256, 0, stream>>>(d_in[4], w12p, 32, 32, flags, 4);
    prep_w<<<(64 * 32 * 9 + 255) / 256, 256, 0, stream>>>(d_in[7], w21p, 64, 32, flags, 7);
    prep_w<<<(64 * 64 * 9 + 255) / 256, 256, 0, stream>>>(d_in[10], w22p, 64, 64, flags, 10);
    prep_w<<<(128 * 64 * 9 + 255) / 256, 256, 0, stream>>>(d_in[13], w31p, 128, 64, flags, 13);
    prep_w<<<(128 * 128 * 9 + 255) / 256, 256, 0, stream>>>(d_in[16], w32p, 128, 128, flags, 16);

    // L11: 1 -> 32 @ 32x32
    deform_conv<<<dim3(1024, 2), 256, 0, stream>>>(X0, w11p, bufA, d_in[21], 1, 32, 32, 32, flags, 21);
    bn_stats<<<dim3(32, 32), 256, 0, stream>>>(bufA, stats + 0 * 256, 131072);
    bn_apply<<<dim3(32, 32), 256, 0, stream>>>(bufA, stats + 0 * 256, d_in[2], d_in[3], 131072, flags, 2, 3);
    // L12: 32 -> 32 @ 32x32
    deform_conv<<<dim3(1024, 2), 256, 0, stream>>>(bufA, w12p, bufB, d_in[21], 32, 32, 32, 32, flags, 21);
    bn_stats<<<dim3(32, 32), 256, 0, stream>>>(bufB, stats + 1 * 256, 131072);
    bn_apply<<<dim3(32, 32), 256, 0, stream>>>(bufB, stats + 1 * 256, d_in[5], d_in[6], 131072, flags, 5, 6);
    // pool -> bufA [32,16,16,B]
    maxpool2k<<<dim3(256, 32), 128, 0, stream>>>(bufB, bufA, 16, 16);
    // L21: 32 -> 64 @ 16x16
    deform_conv<<<dim3(256, 4), 256, 0, stream>>>(bufA, w21p, bufB, d_in[22], 32, 16, 16, 64, flags, 22);
    bn_stats<<<dim3(64, 32), 256, 0, stream>>>(bufB, stats + 2 * 256, 32768);
    bn_apply<<<dim3(16, 64), 256, 0, stream>>>(bufB, stats + 2 * 256, d_in[8], d_in[9], 32768, flags, 8, 9);
    // L22: 64 -> 64 @ 16x16
    deform_conv<<<dim3(256, 4), 256, 0, stream>>>(bufB, w22p, bufA, d_in[22], 64, 16, 16, 64, flags, 22);
    bn_stats<<<dim3(64, 32), 256, 0, stream>>>(bufA, stats + 3 * 256, 32768);
    bn_apply<<<dim3(16, 64), 256, 0, stream>>>(bufA, stats + 3 * 256, d_in[11], d_in[12], 32768, flags, 11, 12);
    // pool -> bufB [64,8,8,B]
    maxpool2k<<<dim3(64, 64), 128, 0, stream>>>(bufA, bufB, 8, 8);
    // L31: 64 -> 128 @ 8x8
    deform_conv<<<dim3(64, 8), 256, 0, stream>>>(bufB, w31p, bufA, d_in[23], 64, 8, 8, 128, flags, 23);
    bn_stats<<<dim3(128, 32), 256, 0, stream>>>(bufA, stats + 4 * 256, 8192);
    bn_apply<<<dim3(8, 128), 256, 0, stream>>>(bufA, stats + 4 * 256, d_in[14], d_in[15], 8192, flags, 14, 15);
    // L32: 128 -> 128 @ 8x8
    deform_conv<<<dim3(64, 8), 256, 0, stream>>>(bufA, w32p, bufB, d_in[23], 128, 8, 8, 128, flags, 23);
    bn_stats<<<dim3(128, 32), 256, 0, stream>>>(bufB, stats + 5 * 256, 8192);
    bn_apply<<<dim3(8, 128), 256, 0, stream>>>(bufB, stats + 5 * 256, d_in[17], d_in[18], 8192, flags, 17, 18);
    // avg -> M [128,B] f32; FC -> out f32
    avgpool8<<<128, 128, 0, stream>>>(bufB, M);
    fc_kernel<<<10, 256, 0, stream>>>(M, d_in[19], d_in[20], out, flags);
}

// Round 9
// 1653.554 us; speedup vs baseline: 28.9141x; 1.2284x over previous
//
#include <hip/hip_runtime.h>
#include <math.h>

// R9: MFMA implicit-GEMM deformable conv.
//   Activations: [p][b][c] bf16 (channel-innermost).
//   Conv GEMM: C[m=cout][n=batch] += A[m][k] * B[k][n], K = (tap,corner,cin) unfolded (36*Cin).
//     A = W2[(c,k)][m] * bilinear_w (LDS-staged, bf16);  B = X[pix][b][c] direct dwordx4 loads.
//   Frag layouts (guide m89/m120, HW-verified): A[m=lane&15][k=quad*8+j];
//     B[k=quad*8+j][n=lane&15]; C col=lane&15, row=quad*4+reg.
//   L11 (Cin=1) stays VALU. Output f32 (R7). Input dtypes adaptive (R6).

#define BATCH 1024
typedef unsigned short u16;
typedef unsigned int uint;
typedef __attribute__((ext_vector_type(8))) short short8;
typedef __attribute__((ext_vector_type(4))) float f32x4;

__device__ __forceinline__ float b2f(u16 v) {
    return __uint_as_float(((uint)v) << 16);
}
__device__ __forceinline__ float4 b2f4(ushort4 v) {
    return make_float4(b2f(v.x), b2f(v.y), b2f(v.z), b2f(v.w));
}
__device__ __forceinline__ u16 f2b(float f) {  // RNE
    uint u = __float_as_uint(f);
    return (u16)((u + 0x7FFFu + ((u >> 16) & 1u)) >> 16);
}
__device__ __forceinline__ float ldf(const void* p, long long i, int isbf) {
    return isbf ? b2f(((const u16*)p)[i]) : ((const float*)p)[i];
}

struct Ptrs { const void* p[24]; int sz[24]; };

// ---------------- dtype probe (proven R6/R7) ----------------
__global__ __launch_bounds__(256) void probe_dtype(Ptrs P, int* __restrict__ flags)
{
    int t = blockIdx.x;
    bool ones = (t == 2 || t == 5 || t == 8 || t == 11 || t == 14 || t == 17);
    bool inh  = (t == 3 || t == 6 || t == 9 || t == 12 || t == 15 || t == 18 || t == 20);
    if (inh) return;
    const u16* q = (const u16*)P.p[t];
    if (ones) {
        if (threadIdx.x == 0) {
            uint w0 = *(const uint*)q;
            flags[t] = (w0 == 0x3F803F80u) ? 1 : 0;
        }
        return;
    }
    int n = P.sz[t]; if (n > 4096) n = 4096;
    __shared__ int cnt;
    if (threadIdx.x == 0) cnt = 0;
    __syncthreads();
    int local = 0;
    for (int i = threadIdx.x; i < n; i += 256) {
        uint e = (q[i] >> 7) & 0xFFu;
        if (!(e == 0u || (e >= 100u && e <= 140u))) local++;
    }
    atomicAdd(&cnt, local);
    __syncthreads();
    if (threadIdx.x == 0) flags[t] = (cnt * 8 > n) ? 0 : 1;
}

__global__ void fixup_flags(int* __restrict__ flags)
{
    if (threadIdx.x == 0) {
        flags[3] = flags[2];  flags[6] = flags[5];  flags[9] = flags[8];
        flags[12] = flags[11]; flags[15] = flags[14]; flags[18] = flags[17];
        flags[20] = flags[19];
    }
}

// ---------------- sampling table: per (p, tap k, corner j): pixel + weight ----------------
__global__ __launch_bounds__(256) void build_table(
    const void* __restrict__ coords, int H, int W,
    int* __restrict__ tIdx, float* __restrict__ tW,
    const int* __restrict__ flags, int slot)
{
    int fcd = flags[slot];
    int i = blockIdx.x * 256 + threadIdx.x;
    int HW = H * W;
    if (i >= HW * 9) return;
    int p = i / 9, k = i % 9;
    int h = p / W, w = p % W;
    int kh = k / 3, kw = k % 3;
    float py = (float)(h - 1 + kh) + ldf(coords, p * 18 + 2 * k, fcd);
    float px = (float)(w - 1 + kw) + ldf(coords, p * 18 + 2 * k + 1, fcd);
    float y0f = floorf(py), x0f = floorf(px);
    float wy1 = py - y0f, wy0 = 1.0f - wy1;
    float wx1 = px - x0f, wx0 = 1.0f - wx1;
    int y0 = (int)y0f, x0 = (int)x0f;
#pragma unroll
    for (int j = 0; j < 4; ++j) {
        int dy = j >> 1, dx = j & 1;
        int yy = y0 + dy, xx = x0 + dx;
        bool valid = (yy >= 0) && (yy < H) && (xx >= 0) && (xx < W);
        int yc = min(max(yy, 0), H - 1);
        int xc = min(max(xx, 0), W - 1);
        tIdx[i * 4 + j] = yc * W + xc;
        tW[i * 4 + j] = valid ? (dy ? wy1 : wy0) * (dx ? wx1 : wx0) : 0.0f;
    }
}

// ---------------- input: [B,1,32,32] -> bf16 X0[pix][b] ----------------
__global__ __launch_bounds__(256) void transpose_in(
    const void* __restrict__ x, u16* __restrict__ X0, const int* __restrict__ flags)
{
    int fx = flags[0];
    int p = blockIdx.x;
    int t = threadIdx.x;
    ushort4 v;
    v.x = f2b(ldf(x, (long long)(4 * t + 0) * 1024 + p, fx));
    v.y = f2b(ldf(x, (long long)(4 * t + 1) * 1024 + p, fx));
    v.z = f2b(ldf(x, (long long)(4 * t + 2) * 1024 + p, fx));
    v.w = f2b(ldf(x, (long long)(4 * t + 3) * 1024 + p, fx));
    ((ushort4*)(X0 + (size_t)p * BATCH))[t] = v;
}

// ---------------- weight prep: [Cout][Cin][3][3] -> f32 [c*9+k][Cout] ----------------
__global__ __launch_bounds__(256) void prep_w(
    const void* __restrict__ W, float* __restrict__ W2, int Cout, int Cin,
    const int* __restrict__ flags, int slot)
{
    int fw = flags[slot];
    int i = blockIdx.x * 256 + threadIdx.x;
    int n = Cout * Cin * 9;
    if (i >= n) return;
    int o = i / (Cin * 9);
    int r = i % (Cin * 9);
    int c = r / 9, k = r % 9;
    W2[(c * 9 + k) * Cout + o] = ldf(W, i, fw);
}

// ---------------- L11 VALU conv (Cin=1): X0[pix][b] -> Y[p][b][32] ----------------
__global__ __launch_bounds__(256) void conv_l11(
    const u16* __restrict__ X0, const float* __restrict__ W2,
    u16* __restrict__ Y, const int* __restrict__ tIdx, const float* __restrict__ tW)
{
    const int p = blockIdx.x;
    const int oBase = blockIdx.y * 16;
    const int b4 = threadIdx.x;
    const ushort4* Xu = (const ushort4*)X0;

    float4 acc[16];
#pragma unroll
    for (int o = 0; o < 16; ++o) acc[o] = make_float4(0.f, 0.f, 0.f, 0.f);

#pragma unroll
    for (int k = 0; k < 9; ++k) {
        float4 s = make_float4(0.f, 0.f, 0.f, 0.f);
#pragma unroll
        for (int j = 0; j < 4; ++j) {
            float wgt = tW[p * 36 + k * 4 + j];
            int pix = tIdx[p * 36 + k * 4 + j];
            float4 v = b2f4(Xu[pix * 256 + b4]);
            s.x = fmaf(wgt, v.x, s.x); s.y = fmaf(wgt, v.y, s.y);
            s.z = fmaf(wgt, v.z, s.z); s.w = fmaf(wgt, v.w, s.w);
        }
#pragma unroll
        for (int o = 0; o < 16; ++o) {
            float wv = W2[k * 32 + oBase + o];
            acc[o].x = fmaf(wv, s.x, acc[o].x); acc[o].y = fmaf(wv, s.y, acc[o].y);
            acc[o].z = fmaf(wv, s.z, acc[o].z); acc[o].w = fmaf(wv, s.w, acc[o].w);
        }
    }
#pragma unroll
    for (int bb = 0; bb < 4; ++bb) {
        u16 h[16];
#pragma unroll
        for (int o = 0; o < 16; ++o) h[o] = f2b((&acc[o].x)[bb]);
        uint4 pk;
        pk.x = (uint)h[0] | ((uint)h[1] << 16);
        pk.y = (uint)h[2] | ((uint)h[3] << 16);
        pk.z = (uint)h[4] | ((uint)h[5] << 16);
        pk.w = (uint)h[6] | ((uint)h[7] << 16);
        uint4 pk2;
        pk2.x = (uint)h[8] | ((uint)h[9] << 16);
        pk2.y = (uint)h[10] | ((uint)h[11] << 16);
        pk2.z = (uint)h[12] | ((uint)h[13] << 16);
        pk2.w = (uint)h[14] | ((uint)h[15] << 16);
        size_t base = ((size_t)p * 1024 + 4 * b4 + bb) * 32 + oBase;
        *(uint4*)(Y + base) = pk;
        *(uint4*)(Y + base + 8) = pk2;
    }
}

// ---------------- MFMA conv ----------------
// X: bf16 [pix][b][Cin]; W2: f32 [c*9+k][Cout]; Y: bf16 [p][b][Cout].
// Wave tile: (MF*16) x (NF*16). 4 waves; GM=2 -> 2x2 (block 128x128), GM=1 -> 1x4.
template<int MF, int NF>
__global__ __launch_bounds__(256) void conv_mfma(
    const u16* __restrict__ X, const float* __restrict__ W2,
    u16* __restrict__ Y,
    const int* __restrict__ tIdx, const float* __restrict__ tW,
    int Cin, int Cout, int csh, int GM)
{
    __shared__ u16 A_lds[128 * 40];   // max Cout x 32, pitch 40 u16 (80 B, 16B-aligned rows)

    const int p = blockIdx.x;
    const int tid = threadIdx.x;
    const int wid = tid >> 6;
    const int lane = tid & 63;
    const int quad = lane >> 4;
    const int l16 = lane & 15;

    const int BNBLK = (4 / GM) * (NF * 16);
    const int nb = blockIdx.y * BNBLK;
    const int wm = (GM == 2) ? (wid & 1) * (MF * 16) : 0;
    const int wn = (GM == 2) ? (wid >> 1) * (NF * 16) : wid * (NF * 16);

    // per-lane B batch offsets (element index pre-multiplied by Cin)
    size_t bCin[NF];
#pragma unroll
    for (int nf = 0; nf < NF; ++nf)
        bCin[nf] = (size_t)(nb + wn + nf * 16 + l16) * Cin;
    // per-lane A LDS offsets
    int aoff[MF];
#pragma unroll
    for (int mf = 0; mf < MF; ++mf)
        aoff[mf] = (wm + mf * 16 + l16) * 40 + quad * 8;

    f32x4 acc[MF][NF];
#pragma unroll
    for (int mf = 0; mf < MF; ++mf)
#pragma unroll
        for (int nf = 0; nf < NF; ++nf)
            acc[mf][nf] = (f32x4){0.f, 0.f, 0.f, 0.f};

    const int nstage = (Cout * 32) >> 8;  // elements per thread for A staging
    const int nc = Cin >> 5;

    for (int cc = 0; cc < nc; ++cc) {
        int c0 = cc << 5;
        for (int kj = 0; kj < 36; ++kj) {
            float wgt = __uint_as_float(__builtin_amdgcn_readfirstlane(
                __float_as_uint(tW[p * 36 + kj])));
            if (wgt == 0.0f) continue;
            int pix = __builtin_amdgcn_readfirstlane(tIdx[p * 36 + kj]);
            int k = kj >> 2;

            __syncthreads();
            // stage A[m][kk] = W2[(c0+kk)*9+k][m] * wgt  (bf16)
            for (int e = 0; e < nstage; ++e) {
                int idx = tid + (e << 8);
                int m = idx & (Cout - 1);
                int kk = idx >> csh;
                float v = W2[(size_t)((c0 + kk) * 9 + k) * Cout + m] * wgt;
                A_lds[m * 40 + kk] = f2b(v);
            }
            __syncthreads();

            // B frags: direct global dwordx4 (8 consecutive c)
            const u16* xp = X + (size_t)pix * 1024 * Cin + c0 + quad * 8;
            short8 bf[NF];
#pragma unroll
            for (int nf = 0; nf < NF; ++nf)
                bf[nf] = *(const short8*)(xp + bCin[nf]);
            // A frags from LDS
            short8 af[MF];
#pragma unroll
            for (int mf = 0; mf < MF; ++mf)
                af[mf] = *(const short8*)(A_lds + aoff[mf]);
#pragma unroll
            for (int mf = 0; mf < MF; ++mf)
#pragma unroll
                for (int nf = 0; nf < NF; ++nf)
                    acc[mf][nf] = __builtin_amdgcn_mfma_f32_16x16x32_bf16(
                        af[mf], bf[nf], acc[mf][nf], 0, 0, 0);
        }
    }

    // epilogue: C col=lane&15 (n), row=quad*4+reg (m)
#pragma unroll
    for (int mf = 0; mf < MF; ++mf) {
        int cout0 = wm + mf * 16 + quad * 4;
#pragma unroll
        for (int nf = 0; nf < NF; ++nf) {
            int b = nb + wn + nf * 16 + l16;
            ushort4 pk;
            pk.x = f2b(acc[mf][nf][0]);
            pk.y = f2b(acc[mf][nf][1]);
            pk.z = f2b(acc[mf][nf][2]);
            pk.w = f2b(acc[mf][nf][3]);
            *(ushort4*)(Y + ((size_t)p * 1024 + b) * Cout + cout0) = pk;
        }
    }
}

// ---------------- BN stats on [row=(p,b)][C] bf16 ----------------
__global__ __launch_bounds__(256) void bn_stats2(
    const u16* __restrict__ Y, float* __restrict__ stats, int Cin, long long NPB)
{
    const int stride = Cin >> 3;           // threads per row (8 c each)
    const int RPI = 256 / stride;
    const int t = threadIdx.x;
    const int cg = t % stride;
    const int r = t / stride;
    const int lane = t & 63;
    const int wid = t >> 6;

    float s[8], q[8];
#pragma unroll
    for (int j = 0; j < 8; ++j) { s[j] = 0.f; q[j] = 0.f; }

    for (long long row0 = (long long)blockIdx.x * RPI; row0 < NPB;
         row0 += (long long)gridDim.x * RPI) {
        long long row = row0 + r;
        if (row >= NPB) continue;
        uint4 v = *(const uint4*)(Y + row * Cin + cg * 8);
        uint ua[4] = {v.x, v.y, v.z, v.w};
#pragma unroll
        for (int jj = 0; jj < 4; ++jj) {
            float lo = __uint_as_float(ua[jj] << 16);
            float hi = __uint_as_float(ua[jj] & 0xFFFF0000u);
            s[2 * jj] += lo;     q[2 * jj] += lo * lo;
            s[2 * jj + 1] += hi; q[2 * jj + 1] += hi * hi;
        }
    }
    // reduce across lanes sharing cg (stride-separated) within the wave
    for (int off = 32; off >= stride; off >>= 1) {
#pragma unroll
        for (int j = 0; j < 8; ++j) {
            s[j] += __shfl_down(s[j], off);
            q[j] += __shfl_down(q[j], off);
        }
    }
    __shared__ float rs[4][128], rq[4][128];
    if (lane < stride) {
#pragma unroll
        for (int j = 0; j < 8; ++j) {
            rs[wid][lane * 8 + j] = s[j];
            rq[wid][lane * 8 + j] = q[j];
        }
    }
    __syncthreads();
    if (t < Cin) {
        float S = rs[0][t] + rs[1][t] + rs[2][t] + rs[3][t];
        float Q = rq[0][t] + rq[1][t] + rq[2][t] + rq[3][t];
        atomicAdd(&stats[2 * t], S);
        atomicAdd(&stats[2 * t + 1], Q);
    }
}

// ---------------- BN apply + ReLU on [row][C] (in place) ----------------
__global__ __launch_bounds__(256) void bn_apply2(
    u16* __restrict__ Y, const float* __restrict__ stats,
    const void* __restrict__ gamma, const void* __restrict__ beta,
    int Cin, float invN, long long total8,
    const int* __restrict__ flags, int gslot, int bslot)
{
    __shared__ float sSC[128], sSH[128];
    int fg = flags[gslot], fb = flags[bslot];
    if (threadIdx.x < Cin) {
        int c = threadIdx.x;
        float mean = stats[2 * c] * invN;
        float var = stats[2 * c + 1] * invN - mean * mean;
        float sc = ldf(gamma, c, fg) * rsqrtf(var + 1e-5f);
        sSC[c] = sc;
        sSH[c] = ldf(beta, c, fb) - mean * sc;
    }
    __syncthreads();
    const int stride = Cin >> 3;
    for (long long i = (long long)blockIdx.x * 256 + threadIdx.x; i < total8;
         i += (long long)gridDim.x * 256) {
        int cg = (int)(i % stride);
        uint4* ptr = (uint4*)(Y + i * 8);
        uint4 v = *ptr;
        uint ua[4] = {v.x, v.y, v.z, v.w};
#pragma unroll
        for (int jj = 0; jj < 4; ++jj) {
            int c = cg * 8 + 2 * jj;
            float lo = __uint_as_float(ua[jj] << 16);
            float hi = __uint_as_float(ua[jj] & 0xFFFF0000u);
            lo = fmaxf(fmaf(lo, sSC[c], sSH[c]), 0.f);
            hi = fmaxf(fmaf(hi, sSC[c + 1], sSH[c + 1]), 0.f);
            ua[jj] = ((uint)f2b(hi) << 16) | (uint)f2b(lo);
        }
        v.x = ua[0]; v.y = ua[1]; v.z = ua[2]; v.w = ua[3];
        *ptr = v;
    }
}

// ---------------- 2x2 maxpool on [p][b][C] ----------------
__global__ __launch_bounds__(256) void maxpool2(
    const u16* __restrict__ A, u16* __restrict__ P, int H2, int W2, int C, long long total)
{
    long long i = (long long)blockIdx.x * 256 + threadIdx.x;
    if (i >= total) return;
    int cgn = C >> 3;
    int cg = (int)(i % cgn);
    long long row = i / cgn;
    int b = (int)(row & 1023);
    int p2 = (int)(row >> 10);
    int h2 = p2 / W2, w2 = p2 % W2;
    int W = 2 * W2;
    int p00 = (2 * h2) * W + 2 * w2;
    const u16* base = A + (size_t)cg * 8;
    uint4 va = *(const uint4*)(base + ((size_t)(p00)*1024 + b) * C);
    uint4 vb = *(const uint4*)(base + ((size_t)(p00 + 1) * 1024 + b) * C);
    uint4 vd = *(const uint4*)(base + ((size_t)(p00 + W) * 1024 + b) * C);
    uint4 ve = *(const uint4*)(base + ((size_t)(p00 + W + 1) * 1024 + b) * C);
    uint ra[4] = {va.x, va.y, va.z, va.w};
    uint rb[4] = {vb.x, vb.y, vb.z, vb.w};
    uint rd[4] = {vd.x, vd.y, vd.z, vd.w};
    uint re[4] = {ve.x, ve.y, ve.z, ve.w};
    uint ro[4];
#pragma unroll
    for (int j = 0; j < 4; ++j) {
        float lo = fmaxf(fmaxf(__uint_as_float(ra[j] << 16), __uint_as_float(rb[j] << 16)),
                         fmaxf(__uint_as_float(rd[j] << 16), __uint_as_float(re[j] << 16)));
        float hi = fmaxf(fmaxf(__uint_as_float(ra[j] & 0xFFFF0000u), __uint_as_float(rb[j] & 0xFFFF0000u)),
                         fmaxf(__uint_as_float(rd[j] & 0xFFFF0000u), __uint_as_float(re[j] & 0xFFFF0000u)));
        ro[j] = ((uint)f2b(hi) << 16) | (uint)f2b(lo);
    }
    uint4 m; m.x = ro[0]; m.y = ro[1]; m.z = ro[2]; m.w = ro[3];
    *(uint4*)(P + ((size_t)p2 * 1024 + b) * C + cg * 8) = m;
}

// ---------------- avg over 64 positions: [p][b][128] -> f32 M[b][128] ----------------
__global__ __launch_bounds__(256) void avgpool2(
    const u16* __restrict__ A, float* __restrict__ M)
{
    int i = blockIdx.x * 256 + threadIdx.x;   // b*16 + cg
    int b = i >> 4, cg = i & 15;
    float s[8];
#pragma unroll
    for (int j = 0; j < 8; ++j) s[j] = 0.f;
    for (int p = 0; p < 64; ++p) {
        uint4 v = *(const uint4*)(A + ((size_t)p * 1024 + b) * 128 + cg * 8);
        uint ua[4] = {v.x, v.y, v.z, v.w};
#pragma unroll
        for (int jj = 0; jj < 4; ++jj) {
            s[2 * jj] += __uint_as_float(ua[jj] << 16);
            s[2 * jj + 1] += __uint_as_float(ua[jj] & 0xFFFF0000u);
        }
    }
#pragma unroll
    for (int j = 0; j < 8; ++j) M[(size_t)b * 128 + cg * 8 + j] = s[j] * (1.0f / 64.0f);
}

// ---------------- FC: out f32 [B,10] from M[b][128] ----------------
__global__ __launch_bounds__(256) void fc_naive(
    const float* __restrict__ M, const void* __restrict__ fcw,
    const void* __restrict__ fcb, float* __restrict__ out, int total,
    const int* __restrict__ flags)
{
    int fw = flags[19], fb = flags[20];
    int i = blockIdx.x * 256 + threadIdx.x;
    if (i >= total) return;
    int o = i % 10, b = i / 10;
    float acc = ldf(fcb, o, fb);
    const float* Mb = M + (size_t)b * 128;
    for (int c = 0; c < 128; ++c) acc = fmaf(Mb[c], ldf(fcw, (size_t)o * 128 + c, fw), acc);
    out[i] = acc;
}

__global__ __launch_bounds__(256) void sentinel_k(float* out, int n, float v) {
    int i = blockIdx.x * 256 + threadIdx.x;
    if (i < n) out[i] = v;
}

extern "C" void kernel_launch(void* const* d_in, const int* in_sizes, int n_in,
                              void* d_out, int out_size, void* d_ws, size_t ws_size,
                              hipStream_t stream) {
    float* out = (float*)d_out;

    static const int exp_sizes[24] = {
        1024 * 1024,
        288, 32, 32,   9216, 32, 32,   18432, 64, 64,   36864, 64, 64,
        73728, 128, 128,   147456, 128, 128,
        1280, 10,   18432, 4608, 1152
    };
    float bad = 0.0f;
    if (n_in != 24) bad = 1000.0f;
    else {
        for (int i = 0; i < 24; ++i)
            if (in_sizes[i] != exp_sizes[i]) { bad = 2000.0f + 16.0f * i; break; }
    }
    if (bad != 0.0f) {
        sentinel_k<<<(out_size + 255) / 256, 256, 0, stream>>>(out, out_size, bad);
        return;
    }

    Ptrs P;
    for (int i = 0; i < 24; ++i) { P.p[i] = d_in[i]; P.sz[i] = in_sizes[i]; }

    char* wsb = (char*)d_ws;
    size_t off = 0;
    auto take = [&](size_t bytes) -> void* {
        void* pp = wsb + off;
        off += (bytes + 255) & ~(size_t)255;
        return pp;
    };
    int*   flags = (int*)  take(32 * 4);
    float* stats = (float*)take(6 * 256 * 4);
    int*   tI32  = (int*)  take(1024 * 36 * 4);
    float* tW32  = (float*)take(1024 * 36 * 4);
    int*   tI16  = (int*)  take(256 * 36 * 4);
    float* tW16  = (float*)take(256 * 36 * 4);
    int*   tI8   = (int*)  take(64 * 36 * 4);
    float* tW8   = (float*)take(64 * 36 * 4);
    float* w11p  = (float*)take(32 * 1 * 9 * 4);
    float* w12p  = (float*)take(32 * 32 * 9 * 4);
    float* w21p  = (float*)take(64 * 32 * 9 * 4);
    float* w22p  = (float*)take(64 * 64 * 9 * 4);
    float* w31p  = (float*)take(128 * 64 * 9 * 4);
    float* w32p  = (float*)take(128 * 128 * 9 * 4);
    u16*   X0    = (u16*)  take((size_t)1024 * BATCH * 2);
    float* M     = (float*)take((size_t)BATCH * 128 * 4);
    u16*   bufA  = (u16*)  take((size_t)32 * 1024 * BATCH * 2);   // 64 MiB
    u16*   bufB  = (u16*)  take((size_t)32 * 1024 * BATCH * 2);   // 64 MiB

    if (ws_size < off) {
        sentinel_k<<<(out_size + 255) / 256, 256, 0, stream>>>(out, out_size, 12345.0f);
        return;
    }

    probe_dtype<<<24, 256, 0, stream>>>(P, flags);
    fixup_flags<<<1, 64, 0, stream>>>(flags);
    hipMemsetAsync(stats, 0, 6 * 256 * 4, stream);
    build_table<<<36, 256, 0, stream>>>(d_in[21], 32, 32, tI32, tW32, flags, 21);
    build_table<<<9, 256, 0, stream>>>(d_in[22], 16, 16, tI16, tW16, flags, 22);
    build_table<<<3, 256, 0, stream>>>(d_in[23], 8, 8, tI8, tW8, flags, 23);
    transpose_in<<<1024, 256, 0, stream>>>(d_in[0], X0, flags);
    prep_w<<<2, 256, 0, stream>>>(d_in[1], w11p, 32, 1, flags, 1);
    prep_w<<<36, 256, 0, stream>>>(d_in[4], w12p, 32, 32, flags, 4);
    prep_w<<<72, 256, 0, stream>>>(d_in[7], w21p, 64, 32, flags, 7);
    prep_w<<<144, 256, 0, stream>>>(d_in[10], w22p, 64, 64, flags, 10);
    prep_w<<<288, 256, 0, stream>>>(d_in[13], w31p, 128, 64, flags, 13);
    prep_w<<<576, 256, 0, stream>>>(d_in[16], w32p, 128, 128, flags, 16);

    // L11: VALU, X0 -> bufA [p][b][32]
    conv_l11<<<dim3(1024, 2), 256, 0, stream>>>(X0, w11p, bufA, tI32, tW32);
    bn_stats2<<<256, 256, 0, stream>>>(bufA, stats + 0 * 256, 32, 1048576LL);
    bn_apply2<<<2048, 256, 0, stream>>>(bufA, stats + 0 * 256, d_in[2], d_in[3], 32,
                                        1.0f / 1048576.0f, 4194304LL, flags, 2, 3);
    // L12: MFMA <2,8>, 32->32 @ 1024 pos
    conv_mfma<2, 8><<<dim3(1024, 2), 256, 0, stream>>>(bufA, w12p, bufB, tI32, tW32, 32, 32, 5, 1);
    bn_stats2<<<256, 256, 0, stream>>>(bufB, stats + 1 * 256, 32, 1048576LL);
    bn_apply2<<<2048, 256, 0, stream>>>(bufB, stats + 1 * 256, d_in[5], d_in[6], 32,
                                        1.0f / 1048576.0f, 4194304LL, flags, 5, 6);
    // pool 32x32 -> 16x16: bufB -> bufA
    maxpool2<<<4096, 256, 0, stream>>>(bufB, bufA, 16, 16, 32, 1048576LL);
    // L21: <4,4> GM=1, 32->64 @ 256 pos
    conv_mfma<4, 4><<<dim3(256, 4), 256, 0, stream>>>(bufA, w21p, bufB, tI16, tW16, 32, 64, 6, 1);
    bn_stats2<<<256, 256, 0, stream>>>(bufB, stats + 2 * 256, 64, 262144LL);
    bn_apply2<<<2048, 256, 0, stream>>>(bufB, stats + 2 * 256, d_in[8], d_in[9], 64,
                                        1.0f / 262144.0f, 2097152LL, flags, 8, 9);
    // L22: 64->64
    conv_mfma<4, 4><<<dim3(256, 4), 256, 0, stream>>>(bufB, w22p, bufA, tI16, tW16, 64, 64, 6, 1);
    bn_stats2<<<256, 256, 0, stream>>>(bufA, stats + 3 * 256, 64, 262144LL);
    bn_apply2<<<2048, 256, 0, stream>>>(bufA, stats + 3 * 256, d_in[11], d_in[12], 64,
                                        1.0f / 262144.0f, 2097152LL, flags, 11, 12);
    // pool 16x16 -> 8x8: bufA -> bufB
    maxpool2<<<2048, 256, 0, stream>>>(bufA, bufB, 8, 8, 64, 524288LL);
    // L31: <4,4> GM=2, 64->128 @ 64 pos
    conv_mfma<4, 4><<<dim3(64, 8), 256, 0, stream>>>(bufB, w31p, bufA, tI8, tW8, 64, 128, 7, 2);
    bn_stats2<<<256, 256, 0, stream>>>(bufA, stats + 4 * 256, 128, 65536LL);
    bn_apply2<<<2048, 256, 0, stream>>>(bufA, stats + 4 * 256, d_in[14], d_in[15], 128,
                                        1.0f / 65536.0f, 1048576LL, flags, 14, 15);
    // L32: 128->128
    conv_mfma<4, 4><<<dim3(64, 8), 256, 0, stream>>>(bufA, w32p, bufB, tI8, tW8, 128, 128, 7, 2);
    bn_stats2<<<256, 256, 0, stream>>>(bufB, stats + 5 * 256, 128, 65536LL);
    bn_apply2<<<2048, 256, 0, stream>>>(bufB, stats + 5 * 256, d_in[17], d_in[18], 128,
                                        1.0f / 65536.0f, 1048576LL, flags, 17, 18);
    // avg -> M[b][128]; FC -> out
    avgpool2<<<64, 256, 0, stream>>>(bufB, M);
    fc_naive<<<40, 256, 0, stream>>>(M, d_in[19], d_in[20], out, 10240, flags);
}

// Round 10
// 1037.645 us; speedup vs baseline: 46.0764x; 1.5936x over previous
//
#include <hip/hip_runtime.h>
#include <math.h>

// R10: conv_mfma v2 — no LDS, no barriers, K = 9*Cin (pre-sampled B).
//   - B frag: bilinear sample built in registers (4 coalesced corner dwordx4
//     + f32 fma + round-half-up pack via v_perm). wgt scaling gone from A.
//   - A frag: one global dwordx4 from prepped bf16 layout Wb[k][c-oct][m][8c]
//     (L1/L2-hot, reused by all blocks). R9's per-kj global-f32 staging + 2
//     syncthreads + scalar-LDS writes (2.5e7 bank conflicts, MfmaUtil 6%) removed.
//   Layout/epilogue/frag mappings identical to R9 (proven). Output f32 (R7),
//   adaptive input dtypes (R6).

#define BATCH 1024
typedef unsigned short u16;
typedef unsigned int uint;
typedef __attribute__((ext_vector_type(8))) short short8;
typedef __attribute__((ext_vector_type(4))) float f32x4;

__device__ __forceinline__ float b2f(u16 v) {
    return __uint_as_float(((uint)v) << 16);
}
__device__ __forceinline__ float4 b2f4(ushort4 v) {
    return make_float4(b2f(v.x), b2f(v.y), b2f(v.z), b2f(v.w));
}
__device__ __forceinline__ u16 f2b(float f) {  // RNE
    uint u = __float_as_uint(f);
    return (u16)((u + 0x7FFFu + ((u >> 16) & 1u)) >> 16);
}
__device__ __forceinline__ float ldf(const void* p, long long i, int isbf) {
    return isbf ? b2f(((const u16*)p)[i]) : ((const float*)p)[i];
}

struct Ptrs { const void* p[24]; int sz[24]; };

// ---------------- dtype probe (proven R6/R7) ----------------
__global__ __launch_bounds__(256) void probe_dtype(Ptrs P, int* __restrict__ flags)
{
    int t = blockIdx.x;
    bool ones = (t == 2 || t == 5 || t == 8 || t == 11 || t == 14 || t == 17);
    bool inh  = (t == 3 || t == 6 || t == 9 || t == 12 || t == 15 || t == 18 || t == 20);
    if (inh) return;
    const u16* q = (const u16*)P.p[t];
    if (ones) {
        if (threadIdx.x == 0) {
            uint w0 = *(const uint*)q;
            flags[t] = (w0 == 0x3F803F80u) ? 1 : 0;
        }
        return;
    }
    int n = P.sz[t]; if (n > 4096) n = 4096;
    __shared__ int cnt;
    if (threadIdx.x == 0) cnt = 0;
    __syncthreads();
    int local = 0;
    for (int i = threadIdx.x; i < n; i += 256) {
        uint e = (q[i] >> 7) & 0xFFu;
        if (!(e == 0u || (e >= 100u && e <= 140u))) local++;
    }
    atomicAdd(&cnt, local);
    __syncthreads();
    if (threadIdx.x == 0) flags[t] = (cnt * 8 > n) ? 0 : 1;
}

__global__ void fixup_flags(int* __restrict__ flags)
{
    if (threadIdx.x == 0) {
        flags[3] = flags[2];  flags[6] = flags[5];  flags[9] = flags[8];
        flags[12] = flags[11]; flags[15] = flags[14]; flags[18] = flags[17];
        flags[20] = flags[19];
    }
}

// ---------------- sampling table ----------------
__global__ __launch_bounds__(256) void build_table(
    const void* __restrict__ coords, int H, int W,
    int* __restrict__ tIdx, float* __restrict__ tW,
    const int* __restrict__ flags, int slot)
{
    int fcd = flags[slot];
    int i = blockIdx.x * 256 + threadIdx.x;
    int HW = H * W;
    if (i >= HW * 9) return;
    int p = i / 9, k = i % 9;
    int h = p / W, w = p % W;
    int kh = k / 3, kw = k % 3;
    float py = (float)(h - 1 + kh) + ldf(coords, p * 18 + 2 * k, fcd);
    float px = (float)(w - 1 + kw) + ldf(coords, p * 18 + 2 * k + 1, fcd);
    float y0f = floorf(py), x0f = floorf(px);
    float wy1 = py - y0f, wy0 = 1.0f - wy1;
    float wx1 = px - x0f, wx0 = 1.0f - wx1;
    int y0 = (int)y0f, x0 = (int)x0f;
#pragma unroll
    for (int j = 0; j < 4; ++j) {
        int dy = j >> 1, dx = j & 1;
        int yy = y0 + dy, xx = x0 + dx;
        bool valid = (yy >= 0) && (yy < H) && (xx >= 0) && (xx < W);
        int yc = min(max(yy, 0), H - 1);
        int xc = min(max(xx, 0), W - 1);
        tIdx[i * 4 + j] = yc * W + xc;
        tW[i * 4 + j] = valid ? (dy ? wy1 : wy0) * (dx ? wx1 : wx0) : 0.0f;
    }
}

// ---------------- input: [B,1,32,32] -> bf16 X0[pix][b] ----------------
__global__ __launch_bounds__(256) void transpose_in(
    const void* __restrict__ x, u16* __restrict__ X0, const int* __restrict__ flags)
{
    int fx = flags[0];
    int p = blockIdx.x;
    int t = threadIdx.x;
    ushort4 v;
    v.x = f2b(ldf(x, (long long)(4 * t + 0) * 1024 + p, fx));
    v.y = f2b(ldf(x, (long long)(4 * t + 1) * 1024 + p, fx));
    v.z = f2b(ldf(x, (long long)(4 * t + 2) * 1024 + p, fx));
    v.w = f2b(ldf(x, (long long)(4 * t + 3) * 1024 + p, fx));
    ((ushort4*)(X0 + (size_t)p * BATCH))[t] = v;
}

// ---------------- weight prep (L11, f32): [Cout][1][3][3] -> [k][Cout] ----------------
__global__ __launch_bounds__(256) void prep_w(
    const void* __restrict__ W, float* __restrict__ W2, int Cout, int Cin,
    const int* __restrict__ flags, int slot)
{
    int fw = flags[slot];
    int i = blockIdx.x * 256 + threadIdx.x;
    int n = Cout * Cin * 9;
    if (i >= n) return;
    int o = i / (Cin * 9);
    int r = i % (Cin * 9);
    int c = r / 9, k = r % 9;
    W2[(c * 9 + k) * Cout + o] = ldf(W, i, fw);
}

// ---------------- weight prep (MFMA, bf16): raw -> Wb[k][c-oct][m][8c] ----------------
__global__ __launch_bounds__(256) void prep_wb(
    const void* __restrict__ W, u16* __restrict__ Wb, int Cout, int Cin,
    const int* __restrict__ flags, int slot)
{
    int fw = flags[slot];
    int i = blockIdx.x * 256 + threadIdx.x;
    int n = Cout * Cin * 9;
    if (i >= n) return;
    int c8 = i & 7;
    int r = i >> 3;
    int m = r % Cout;
    int r2 = r / Cout;
    int noct = Cin >> 3;
    int oc = r2 % noct;
    int k = r2 / noct;
    int c = oc * 8 + c8;
    Wb[i] = f2b(ldf(W, (long long)m * Cin * 9 + c * 9 + k, fw));
}

// ---------------- L11 VALU conv (Cin=1): X0[pix][b] -> Y[p][b][32] ----------------
__global__ __launch_bounds__(256) void conv_l11(
    const u16* __restrict__ X0, const float* __restrict__ W2,
    u16* __restrict__ Y, const int* __restrict__ tIdx, const float* __restrict__ tW)
{
    const int p = blockIdx.x;
    const int oBase = blockIdx.y * 16;
    const int b4 = threadIdx.x;
    const ushort4* Xu = (const ushort4*)X0;

    float4 acc[16];
#pragma unroll
    for (int o = 0; o < 16; ++o) acc[o] = make_float4(0.f, 0.f, 0.f, 0.f);

#pragma unroll
    for (int k = 0; k < 9; ++k) {
        float4 s = make_float4(0.f, 0.f, 0.f, 0.f);
#pragma unroll
        for (int j = 0; j < 4; ++j) {
            float wgt = tW[p * 36 + k * 4 + j];
            int pix = tIdx[p * 36 + k * 4 + j];
            float4 v = b2f4(Xu[pix * 256 + b4]);
            s.x = fmaf(wgt, v.x, s.x); s.y = fmaf(wgt, v.y, s.y);
            s.z = fmaf(wgt, v.z, s.z); s.w = fmaf(wgt, v.w, s.w);
        }
#pragma unroll
        for (int o = 0; o < 16; ++o) {
            float wv = W2[k * 32 + oBase + o];
            acc[o].x = fmaf(wv, s.x, acc[o].x); acc[o].y = fmaf(wv, s.y, acc[o].y);
            acc[o].z = fmaf(wv, s.z, acc[o].z); acc[o].w = fmaf(wv, s.w, acc[o].w);
        }
    }
#pragma unroll
    for (int bb = 0; bb < 4; ++bb) {
        u16 h[16];
#pragma unroll
        for (int o = 0; o < 16; ++o) h[o] = f2b((&acc[o].x)[bb]);
        uint4 pk;
        pk.x = (uint)h[0] | ((uint)h[1] << 16);
        pk.y = (uint)h[2] | ((uint)h[3] << 16);
        pk.z = (uint)h[4] | ((uint)h[5] << 16);
        pk.w = (uint)h[6] | ((uint)h[7] << 16);
        uint4 pk2;
        pk2.x = (uint)h[8] | ((uint)h[9] << 16);
        pk2.y = (uint)h[10] | ((uint)h[11] << 16);
        pk2.z = (uint)h[12] | ((uint)h[13] << 16);
        pk2.w = (uint)h[14] | ((uint)h[15] << 16);
        size_t base = ((size_t)p * 1024 + 4 * b4 + bb) * 32 + oBase;
        *(uint4*)(Y + base) = pk;
        *(uint4*)(Y + base + 8) = pk2;
    }
}

// ---------------- MFMA conv v2 ----------------
// X: bf16 [pix][b][Cin]; Wb: bf16 [k][c-oct][m][8c]; Y: bf16 [p][b][Cout].
// GM=1: 4 waves n-split (NB=4*NF*16); GM=2: 2x2 waves (NB=2*NF*16).
template<int MF, int NF, int GM>
__global__ __launch_bounds__(256) void conv_mfma(
    const u16* __restrict__ X, const u16* __restrict__ Wb,
    u16* __restrict__ Y,
    const int* __restrict__ tIdx, const float* __restrict__ tW,
    int Cin, int Cout)
{
    const int p = blockIdx.x;
    const int tid = threadIdx.x;
    const int wid = tid >> 6;
    const int lane = tid & 63;
    const int quad = lane >> 4;
    const int l16 = lane & 15;

    const int NB = (GM == 2 ? 2 : 4) * (NF * 16);
    const int nb = blockIdx.y * NB;
    const int wm = (GM == 2) ? (wid & 1) * (MF * 16) : 0;
    const int wn = (GM == 2) ? (wid >> 1) * (NF * 16) : wid * (NF * 16);

    const int noct = Cin >> 3;
    const size_t pixstride = (size_t)1024 * Cin;

    int roff[NF];
#pragma unroll
    for (int nf = 0; nf < NF; ++nf)
        roff[nf] = (nb + wn + nf * 16 + l16) * Cin + quad * 8;

    f32x4 acc[MF][NF];
#pragma unroll
    for (int mf = 0; mf < MF; ++mf)
#pragma unroll
        for (int nf = 0; nf < NF; ++nf)
            acc[mf][nf] = (f32x4){0.f, 0.f, 0.f, 0.f};

    const int nc = Cin >> 5;
    for (int k = 0; k < 9; ++k) {
        int pix[4]; float ww[4];
#pragma unroll
        for (int j = 0; j < 4; ++j) {
            pix[j] = __builtin_amdgcn_readfirstlane(tIdx[p * 36 + k * 4 + j]);
            ww[j] = __uint_as_float(__builtin_amdgcn_readfirstlane(
                __float_as_uint(tW[p * 36 + k * 4 + j])));
        }
        const u16* xb0 = X + (size_t)pix[0] * pixstride;
        const u16* xb1 = X + (size_t)pix[1] * pixstride;
        const u16* xb2 = X + (size_t)pix[2] * pixstride;
        const u16* xb3 = X + (size_t)pix[3] * pixstride;

        for (int cc = 0; cc < nc; ++cc) {
            const int coff = cc << 5;
            // ---- B frags: bilinear sample in f32, pack bf16 (round-half-up) ----
            short8 bf[NF];
#pragma unroll
            for (int nf = 0; nf < NF; ++nf) {
                int ro = roff[nf] + coff;
                uint4 v0 = *(const uint4*)(xb0 + ro);
                uint4 v1 = *(const uint4*)(xb1 + ro);
                uint4 v2 = *(const uint4*)(xb2 + ro);
                uint4 v3 = *(const uint4*)(xb3 + ro);
                const uint* a0 = &v0.x; const uint* a1 = &v1.x;
                const uint* a2 = &v2.x; const uint* a3 = &v3.x;
                union { short8 s; uint4 u; } cvt;
                uint o[4];
#pragma unroll
                for (int i = 0; i < 4; ++i) {
                    float sl = ww[0] * __uint_as_float(a0[i] << 16);
                    float sh = ww[0] * __uint_as_float(a0[i] & 0xFFFF0000u);
                    sl = fmaf(ww[1], __uint_as_float(a1[i] << 16), sl);
                    sh = fmaf(ww[1], __uint_as_float(a1[i] & 0xFFFF0000u), sh);
                    sl = fmaf(ww[2], __uint_as_float(a2[i] << 16), sl);
                    sh = fmaf(ww[2], __uint_as_float(a2[i] & 0xFFFF0000u), sh);
                    sl = fmaf(ww[3], __uint_as_float(a3[i] << 16), sl);
                    sh = fmaf(ww[3], __uint_as_float(a3[i] & 0xFFFF0000u), sh);
                    o[i] = __builtin_amdgcn_perm(
                        __float_as_uint(sh) + 0x8000u,
                        __float_as_uint(sl) + 0x8000u, 0x07060302u);
                }
                cvt.u.x = o[0]; cvt.u.y = o[1]; cvt.u.z = o[2]; cvt.u.w = o[3];
                bf[nf] = cvt.s;
            }
            // ---- A frags (global, L1/L2-hot) + MFMA ----
#pragma unroll
            for (int mf = 0; mf < MF; ++mf) {
                const short8 af = *(const short8*)(Wb +
                    ((size_t)((k * noct + (cc << 2) + quad) * Cout + wm + mf * 16 + l16)) * 8);
#pragma unroll
                for (int nf = 0; nf < NF; ++nf)
                    acc[mf][nf] = __builtin_amdgcn_mfma_f32_16x16x32_bf16(
                        af, bf[nf], acc[mf][nf], 0, 0, 0);
            }
        }
    }

    // epilogue: C col=lane&15 (n), row=quad*4+reg (m)  [proven R9]
#pragma unroll
    for (int mf = 0; mf < MF; ++mf) {
        int cout0 = wm + mf * 16 + quad * 4;
#pragma unroll
        for (int nf = 0; nf < NF; ++nf) {
            int b = nb + wn + nf * 16 + l16;
            ushort4 pk;
            pk.x = f2b(acc[mf][nf][0]);
            pk.y = f2b(acc[mf][nf][1]);
            pk.z = f2b(acc[mf][nf][2]);
            pk.w = f2b(acc[mf][nf][3]);
            *(ushort4*)(Y + ((size_t)p * 1024 + b) * Cout + cout0) = pk;
        }
    }
}

// ---------------- BN stats on [row=(p,b)][C] bf16 (proven R9) ----------------
__global__ __launch_bounds__(256) void bn_stats2(
    const u16* __restrict__ Y, float* __restrict__ stats, int Cin, long long NPB)
{
    const int stride = Cin >> 3;
    const int RPI = 256 / stride;
    const int t = threadIdx.x;
    const int cg = t % stride;
    const int r = t / stride;
    const int lane = t & 63;
    const int wid = t >> 6;

    float s[8], q[8];
#pragma unroll
    for (int j = 0; j < 8; ++j) { s[j] = 0.f; q[j] = 0.f; }

    for (long long row0 = (long long)blockIdx.x * RPI; row0 < NPB;
         row0 += (long long)gridDim.x * RPI) {
        long long row = row0 + r;
        if (row >= NPB) continue;
        uint4 v = *(const uint4*)(Y + row * Cin + cg * 8);
        uint ua[4] = {v.x, v.y, v.z, v.w};
#pragma unroll
        for (int jj = 0; jj < 4; ++jj) {
            float lo = __uint_as_float(ua[jj] << 16);
            float hi = __uint_as_float(ua[jj] & 0xFFFF0000u);
            s[2 * jj] += lo;     q[2 * jj] += lo * lo;
            s[2 * jj + 1] += hi; q[2 * jj + 1] += hi * hi;
        }
    }
    for (int off = 32; off >= stride; off >>= 1) {
#pragma unroll
        for (int j = 0; j < 8; ++j) {
            s[j] += __shfl_down(s[j], off);
            q[j] += __shfl_down(q[j], off);
        }
    }
    __shared__ float rs[4][128], rq[4][128];
    if (lane < stride) {
#pragma unroll
        for (int j = 0; j < 8; ++j) {
            rs[wid][lane * 8 + j] = s[j];
            rq[wid][lane * 8 + j] = q[j];
        }
    }
    __syncthreads();
    if (t < Cin) {
        float S = rs[0][t] + rs[1][t] + rs[2][t] + rs[3][t];
        float Q = rq[0][t] + rq[1][t] + rq[2][t] + rq[3][t];
        atomicAdd(&stats[2 * t], S);
        atomicAdd(&stats[2 * t + 1], Q);
    }
}

// ---------------- BN apply + ReLU on [row][C] (proven R9) ----------------
__global__ __launch_bounds__(256) void bn_apply2(
    u16* __restrict__ Y, const float* __restrict__ stats,
    const void* __restrict__ gamma, const void* __restrict__ beta,
    int Cin, float invN, long long total8,
    const int* __restrict__ flags, int gslot, int bslot)
{
    __shared__ float sSC[128], sSH[128];
    int fg = flags[gslot], fb = flags[bslot];
    if (threadIdx.x < Cin) {
        int c = threadIdx.x;
        float mean = stats[2 * c] * invN;
        float var = stats[2 * c + 1] * invN - mean * mean;
        float sc = ldf(gamma, c, fg) * rsqrtf(var + 1e-5f);
        sSC[c] = sc;
        sSH[c] = ldf(beta, c, fb) - mean * sc;
    }
    __syncthreads();
    const int stride = Cin >> 3;
    for (long long i = (long long)blockIdx.x * 256 + threadIdx.x; i < total8;
         i += (long long)gridDim.x * 256) {
        int cg = (int)(i % stride);
        uint4* ptr = (uint4*)(Y + i * 8);
        uint4 v = *ptr;
        uint ua[4] = {v.x, v.y, v.z, v.w};
#pragma unroll
        for (int jj = 0; jj < 4; ++jj) {
            int c = cg * 8 + 2 * jj;
            float lo = __uint_as_float(ua[jj] << 16);
            float hi = __uint_as_float(ua[jj] & 0xFFFF0000u);
            lo = fmaxf(fmaf(lo, sSC[c], sSH[c]), 0.f);
            hi = fmaxf(fmaf(hi, sSC[c + 1], sSH[c + 1]), 0.f);
            ua[jj] = ((uint)f2b(hi) << 16) | (uint)f2b(lo);
        }
        v.x = ua[0]; v.y = ua[1]; v.z = ua[2]; v.w = ua[3];
        *ptr = v;
    }
}

// ---------------- 2x2 maxpool on [p][b][C] (proven R9) ----------------
__global__ __launch_bounds__(256) void maxpool2(
    const u16* __restrict__ A, u16* __restrict__ P, int H2, int W2, int C, long long total)
{
    long long i = (long long)blockIdx.x * 256 + threadIdx.x;
    if (i >= total) return;
    int cgn = C >> 3;
    int cg = (int)(i % cgn);
    long long row = i / cgn;
    int b = (int)(row & 1023);
    int p2 = (int)(row >> 10);
    int h2 = p2 / W2, w2 = p2 % W2;
    int W = 2 * W2;
    int p00 = (2 * h2) * W + 2 * w2;
    const u16* base = A + (size_t)cg * 8;
    uint4 va = *(const uint4*)(base + ((size_t)(p00)*1024 + b) * C);
    uint4 vb = *(const uint4*)(base + ((size_t)(p00 + 1) * 1024 + b) * C);
    uint4 vd = *(const uint4*)(base + ((size_t)(p00 + W) * 1024 + b) * C);
    uint4 ve = *(const uint4*)(base + ((size_t)(p00 + W + 1) * 1024 + b) * C);
    uint ra[4] = {va.x, va.y, va.z, va.w};
    uint rb[4] = {vb.x, vb.y, vb.z, vb.w};
    uint rd[4] = {vd.x, vd.y, vd.z, vd.w};
    uint re[4] = {ve.x, ve.y, ve.z, ve.w};
    uint ro[4];
#pragma unroll
    for (int j = 0; j < 4; ++j) {
        float lo = fmaxf(fmaxf(__uint_as_float(ra[j] << 16), __uint_as_float(rb[j] << 16)),
                         fmaxf(__uint_as_float(rd[j] << 16), __uint_as_float(re[j] << 16)));
        float hi = fmaxf(fmaxf(__uint_as_float(ra[j] & 0xFFFF0000u), __uint_as_float(rb[j] & 0xFFFF0000u)),
                         fmaxf(__uint_as_float(rd[j] & 0xFFFF0000u), __uint_as_float(re[j] & 0xFFFF0000u)));
        ro[j] = ((uint)f2b(hi) << 16) | (uint)f2b(lo);
    }
    uint4 m; m.x = ro[0]; m.y = ro[1]; m.z = ro[2]; m.w = ro[3];
    *(uint4*)(P + ((size_t)p2 * 1024 + b) * C + cg * 8) = m;
}

// ---------------- avg over 64 positions: [p][b][128] -> f32 M[b][128] ----------------
__global__ __launch_bounds__(256) void avgpool2(
    const u16* __restrict__ A, float* __restrict__ M)
{
    int i = blockIdx.x * 256 + threadIdx.x;   // b*16 + cg
    int b = i >> 4, cg = i & 15;
    float s[8];
#pragma unroll
    for (int j = 0; j < 8; ++j) s[j] = 0.f;
    for (int p = 0; p < 64; ++p) {
        uint4 v = *(const uint4*)(A + ((size_t)p * 1024 + b) * 128 + cg * 8);
        uint ua[4] = {v.x, v.y, v.z, v.w};
#pragma unroll
        for (int jj = 0; jj < 4; ++jj) {
            s[2 * jj] += __uint_as_float(ua[jj] << 16);
            s[2 * jj + 1] += __uint_as_float(ua[jj] & 0xFFFF0000u);
        }
    }
#pragma unroll
    for (int j = 0; j < 8; ++j) M[(size_t)b * 128 + cg * 8 + j] = s[j] * (1.0f / 64.0f);
}

// ---------------- FC: out f32 [B,10] from M[b][128] ----------------
__global__ __launch_bounds__(256) void fc_naive(
    const float* __restrict__ M, const void* __restrict__ fcw,
    const void* __restrict__ fcb, float* __restrict__ out, int total,
    const int* __restrict__ flags)
{
    int fw = flags[19], fb = flags[20];
    int i = blockIdx.x * 256 + threadIdx.x;
    if (i >= total) return;
    int o = i % 10, b = i / 10;
    float acc = ldf(fcb, o, fb);
    const float* Mb = M + (size_t)b * 128;
    for (int c = 0; c < 128; ++c) acc = fmaf(Mb[c], ldf(fcw, (size_t)o * 128 + c, fw), acc);
    out[i] = acc;
}

__global__ __launch_bounds__(256) void sentinel_k(float* out, int n, float v) {
    int i = blockIdx.x * 256 + threadIdx.x;
    if (i < n) out[i] = v;
}

extern "C" void kernel_launch(void* const* d_in, const int* in_sizes, int n_in,
                              void* d_out, int out_size, void* d_ws, size_t ws_size,
                              hipStream_t stream) {
    float* out = (float*)d_out;

    static const int exp_sizes[24] = {
        1024 * 1024,
        288, 32, 32,   9216, 32, 32,   18432, 64, 64,   36864, 64, 64,
        73728, 128, 128,   147456, 128, 128,
        1280, 10,   18432, 4608, 1152
    };
    float bad = 0.0f;
    if (n_in != 24) bad = 1000.0f;
    else {
        for (int i = 0; i < 24; ++i)
            if (in_sizes[i] != exp_sizes[i]) { bad = 2000.0f + 16.0f * i; break; }
    }
    if (bad != 0.0f) {
        sentinel_k<<<(out_size + 255) / 256, 256, 0, stream>>>(out, out_size, bad);
        return;
    }

    Ptrs P;
    for (int i = 0; i < 24; ++i) { P.p[i] = d_in[i]; P.sz[i] = in_sizes[i]; }

    char* wsb = (char*)d_ws;
    size_t off = 0;
    auto take = [&](size_t bytes) -> void* {
        void* pp = wsb + off;
        off += (bytes + 255) & ~(size_t)255;
        return pp;
    };
    int*   flags = (int*)  take(32 * 4);
    float* stats = (float*)take(6 * 256 * 4);
    int*   tI32  = (int*)  take(1024 * 36 * 4);
    float* tW32  = (float*)take(1024 * 36 * 4);
    int*   tI16  = (int*)  take(256 * 36 * 4);
    float* tW16  = (float*)take(256 * 36 * 4);
    int*   tI8   = (int*)  take(64 * 36 * 4);
    float* tW8   = (float*)take(64 * 36 * 4);
    float* w11p  = (float*)take(32 * 1 * 9 * 4);
    u16*   wb12  = (u16*)  take(32 * 32 * 9 * 2);
    u16*   wb21  = (u16*)  take(64 * 32 * 9 * 2);
    u16*   wb22  = (u16*)  take(64 * 64 * 9 * 2);
    u16*   wb31  = (u16*)  take(128 * 64 * 9 * 2);
    u16*   wb32  = (u16*)  take(128 * 128 * 9 * 2);
    u16*   X0    = (u16*)  take((size_t)1024 * BATCH * 2);
    float* M     = (float*)take((size_t)BATCH * 128 * 4);
    u16*   bufA  = (u16*)  take((size_t)32 * 1024 * BATCH * 2);   // 64 MiB
    u16*   bufB  = (u16*)  take((size_t)32 * 1024 * BATCH * 2);   // 64 MiB

    if (ws_size < off) {
        sentinel_k<<<(out_size + 255) / 256, 256, 0, stream>>>(out, out_size, 12345.0f);
        return;
    }

    probe_dtype<<<24, 256, 0, stream>>>(P, flags);
    fixup_flags<<<1, 64, 0, stream>>>(flags);
    hipMemsetAsync(stats, 0, 6 * 256 * 4, stream);
    build_table<<<36, 256, 0, stream>>>(d_in[21], 32, 32, tI32, tW32, flags, 21);
    build_table<<<9, 256, 0, stream>>>(d_in[22], 16, 16, tI16, tW16, flags, 22);
    build_table<<<3, 256, 0, stream>>>(d_in[23], 8, 8, tI8, tW8, flags, 23);
    transpose_in<<<1024, 256, 0, stream>>>(d_in[0], X0, flags);
    prep_w<<<2, 256, 0, stream>>>(d_in[1], w11p, 32, 1, flags, 1);
    prep_wb<<<36, 256, 0, stream>>>(d_in[4], wb12, 32, 32, flags, 4);
    prep_wb<<<72, 256, 0, stream>>>(d_in[7], wb21, 64, 32, flags, 7);
    prep_wb<<<144, 256, 0, stream>>>(d_in[10], wb22, 64, 64, flags, 10);
    prep_wb<<<288, 256, 0, stream>>>(d_in[13], wb31, 128, 64, flags, 13);
    prep_wb<<<576, 256, 0, stream>>>(d_in[16], wb32, 128, 128, flags, 16);

    // L11: VALU, X0 -> bufA [p][b][32]
    conv_l11<<<dim3(1024, 2), 256, 0, stream>>>(X0, w11p, bufA, tI32, tW32);
    bn_stats2<<<256, 256, 0, stream>>>(bufA, stats + 0 * 256, 32, 1048576LL);
    bn_apply2<<<2048, 256, 0, stream>>>(bufA, stats + 0 * 256, d_in[2], d_in[3], 32,
                                        1.0f / 1048576.0f, 4194304LL, flags, 2, 3);
    // L12: 32->32 @ 1024 pos
    conv_mfma<2, 4, 1><<<dim3(1024, 4), 256, 0, stream>>>(bufA, wb12, bufB, tI32, tW32, 32, 32);
    bn_stats2<<<256, 256, 0, stream>>>(bufB, stats + 1 * 256, 32, 1048576LL);
    bn_apply2<<<2048, 256, 0, stream>>>(bufB, stats + 1 * 256, d_in[5], d_in[6], 32,
                                        1.0f / 1048576.0f, 4194304LL, flags, 5, 6);
    // pool 32x32 -> 16x16
    maxpool2<<<4096, 256, 0, stream>>>(bufB, bufA, 16, 16, 32, 1048576LL);
    // L21: 32->64 @ 256 pos
    conv_mfma<4, 4, 1><<<dim3(256, 4), 256, 0, stream>>>(bufA, wb21, bufB, tI16, tW16, 32, 64);
    bn_stats2<<<256, 256, 0, stream>>>(bufB, stats + 2 * 256, 64, 262144LL);
    bn_apply2<<<2048, 256, 0, stream>>>(bufB, stats + 2 * 256, d_in[8], d_in[9], 64,
                                        1.0f / 262144.0f, 2097152LL, flags, 8, 9);
    // L22: 64->64
    conv_mfma<4, 4, 1><<<dim3(256, 4), 256, 0, stream>>>(bufB, wb22, bufA, tI16, tW16, 64, 64);
    bn_stats2<<<256, 256, 0, stream>>>(bufA, stats + 3 * 256, 64, 262144LL);
    bn_apply2<<<2048, 256, 0, stream>>>(bufA, stats + 3 * 256, d_in[11], d_in[12], 64,
                                        1.0f / 262144.0f, 2097152LL, flags, 11, 12);
    // pool 16x16 -> 8x8
    maxpool2<<<2048, 256, 0, stream>>>(bufA, bufB, 8, 8, 64, 524288LL);
    // L31: 64->128 @ 64 pos
    conv_mfma<4, 4, 2><<<dim3(64, 8), 256, 0, stream>>>(bufB, wb31, bufA, tI8, tW8, 64, 128);
    bn_stats2<<<256, 256, 0, stream>>>(bufA, stats + 4 * 256, 128, 65536LL);
    bn_apply2<<<2048, 256, 0, stream>>>(bufA, stats + 4 * 256, d_in[14], d_in[15], 128,
                                        1.0f / 65536.0f, 1048576LL, flags, 14, 15);
    // L32: 128->128
    conv_mfma<4, 4, 2><<<dim3(64, 8), 256, 0, stream>>>(bufA, wb32, bufB, tI8, tW8, 128, 128);
    bn_stats2<<<256, 256, 0, stream>>>(bufB, stats + 5 * 256, 128, 65536LL);
    bn_apply2<<<2048, 256, 0, stream>>>(bufB, stats + 5 * 256, d_in[17], d_in[18], 128,
                                        1.0f / 65536.0f, 1048576LL, flags, 17, 18);
    // avg + FC
    avgpool2<<<64, 256, 0, stream>>>(bufB, M);
    fc_naive<<<40, 256, 0, stream>>>(M, d_in[19], d_in[20], out, 10240, flags);
}